// Round 14
// baseline (550.286 us; speedup 1.0000x reference)
//
#include <hip/hip_runtime.h>

#define N_NODES 100000
#define N_EDGES 1600000
#define N_GRAPHS 1024
#define HID 64
#define MLP_HID 128
#define N_COMBO 264    // 22*6*2 edge-attr combinations
#define NBUCK 98       // ceil(N_NODES / 1024)
#define BCAP 20480     // fixed bucket capacity (mean 16384)
#define CHUNK 6144     // edges per bscatter block (48KB LDS staging)
#define NDBIN 64       // degree bins for balanced gather

#define NB_EMBED 1563  // (N_NODES+63)/64
#define NPREP (3*N_COMBO*HID + 3*MLP_HID*HID + 3*MLP_HID)   // 75648
#define NB_PREP 296    // ceil(NPREP/256)

typedef __attribute__((ext_vector_type(8))) short bf16x8;
typedef __attribute__((ext_vector_type(4))) float f32x4;
typedef __attribute__((ext_vector_type(2))) float f32x2;

static __device__ __forceinline__ float bf2f(unsigned short u) {
    union { unsigned int i; float f; } v; v.i = ((unsigned int)u) << 16; return v.f;
}
static __device__ __forceinline__ unsigned short f2bf(float f) {
    union { float f; unsigned int i; } v; v.f = f;
    unsigned int u = v.i;
    unsigned int r = u + 0x7FFFu + ((u >> 16) & 1u);   // RNE
    return (unsigned short)(r >> 16);
}
static __device__ __forceinline__ f32x2 bfpair(unsigned int u) {
    union { unsigned int i; float f; } lo, hi;
    lo.i = u << 16;
    hi.i = u & 0xFFFF0000u;
    f32x2 r; r.x = lo.f; r.y = hi.f; return r;
}
static __device__ __forceinline__ unsigned int pack2bf(float a, float b) {
    return (unsigned int)f2bf(a) | ((unsigned int)f2bf(b) << 16);
}

// ---------------------------------------------------------------------------
// Fused misc kernel: [0,NB_EMBED) atom-embed + pooled[0];
//                    [NB_EMBED, +NB_PREP) weight/comb prep.
// ---------------------------------------------------------------------------
__global__ __launch_bounds__(256) void misc_kernel(
    const int* __restrict__ x, const float* __restrict__ atom_emb,
    const int* __restrict__ batch, unsigned short* __restrict__ h,
    float* __restrict__ out,
    const float* __restrict__ edge_emb,
    const float* __restrict__ w1, const float* __restrict__ w2,
    const float* __restrict__ b1, const float* __restrict__ bn_g,
    const float* __restrict__ bn_b, const float* __restrict__ bn_m,
    const float* __restrict__ bn_v,
    float* __restrict__ comb,
    unsigned short* __restrict__ w1b, unsigned short* __restrict__ w2b,
    float* __restrict__ alpha, float* __restrict__ beta)
{
    const int bid = blockIdx.x;
    const int tid = threadIdx.x;

    if (bid < NB_EMBED) {
        int f = tid & 63;
        int q = __builtin_amdgcn_readfirstlane(tid >> 6);   // wave-uniform
        int base = bid * 64 + q * 16;
        float run = 0.f;
        int cg = -1;
        for (int k = 0; k < 16; ++k) {
            int gn = base + k;
            if (gn >= N_NODES) break;
            const int* xp = x + gn * 9;                     // uniform -> s_load
            float acc = 0.f;
#pragma unroll
            for (int j = 0; j < 9; ++j) {
                int idx = xp[j];
                acc += atom_emb[(j * 119 + idx) * HID + f]; // coalesced 256B
            }
            h[(size_t)gn * HID + f] = f2bf(acc);
            int g = batch[gn];                              // uniform
            if (g != cg) {
                if (cg >= 0) atomicAdd(&out[cg * 256 + f], run);
                run = 0.f; cg = g;
            }
            run += acc;
        }
        if (cg >= 0) atomicAdd(&out[cg * 256 + f], run);
    } else {
        int t = (bid - NB_EMBED) * 256 + tid;
        const int NC = 3 * N_COMBO * HID;   // 50688
        const int NW = 3 * MLP_HID * HID;   // 24576
        if (t < NC) {
            int d = t & 63;
            int c = (t >> 6) % N_COMBO;
            int l = (t >> 6) / N_COMBO;
            int a0 = c / 12, r = c % 12, a1 = r >> 1, a2 = r & 1;
            const float* base = edge_emb + (size_t)l * 3 * 22 * HID;
            comb[t] = base[(0 * 22 + a0) * HID + d]
                    + base[(1 * 22 + a1) * HID + d]
                    + base[(2 * 22 + a2) * HID + d];
        } else if (t < NC + NW) {
            int i = t - NC;
            w1b[i] = f2bf(w1[i]);
            w2b[i] = f2bf(w2[i]);
        } else if (t < NC + NW + 3 * MLP_HID) {
            int i = t - NC - NW;
            float a = rsqrtf(bn_v[i] + 1e-5f) * bn_g[i];
            alpha[i] = a;
            beta[i] = (b1[i] - bn_m[i]) * a + bn_b[i];
        }
    }
}

// ---------------------------------------------------------------------------
// bscatter: LDS-staged reorder by bucket into fixed-capacity regions.
// ---------------------------------------------------------------------------
__global__ __launch_bounds__(256) void bscatter_kernel(
    const int* __restrict__ ei, const int* __restrict__ ea,
    int* __restrict__ bcur, unsigned long long* __restrict__ ebuf)
{
    __shared__ unsigned long long stage[CHUNK];   // 48 KB
    __shared__ int hist[NBUCK];
    __shared__ int lbase[NBUCK];
    __shared__ int shift[NBUCK];
    __shared__ int sbuf[128];

    int tid = threadIdx.x;
    int base = blockIdx.x * CHUNK;
    int n_here = min(CHUNK, N_EDGES - base);

    for (int i = tid; i < NBUCK; i += 256) hist[i] = 0;
    __syncthreads();
    for (int i = tid; i < n_here; i += 256)
        atomicAdd(&hist[ei[N_EDGES + base + i] >> 10], 1);
    __syncthreads();
    if (tid < 128) sbuf[tid] = (tid < NBUCK) ? hist[tid] : 0;
    __syncthreads();
    for (int s = 1; s < 128; s <<= 1) {
        int u = 0;
        if (tid < 128 && tid >= s) u = sbuf[tid - s];
        __syncthreads();
        if (tid < 128) sbuf[tid] += u;
        __syncthreads();
    }
    if (tid < NBUCK) lbase[tid] = sbuf[tid] - hist[tid];
    __syncthreads();
    if (tid < NBUCK) {
        int c = hist[tid];
        if (c > 0) {
            int g = tid * BCAP + atomicAdd(&bcur[tid], c);
            shift[tid] = g - lbase[tid];
        }
        hist[tid] = lbase[tid];
    }
    __syncthreads();
    for (int i = tid; i < n_here; i += 256) {
        int e = base + i;
        int src = ei[e];
        int dst = ei[N_EDGES + e];
        int combo = (ea[e * 3 + 0] * 6 + ea[e * 3 + 1]) * 2 + ea[e * 3 + 2];
        int pos = atomicAdd(&hist[dst >> 10], 1);
        stage[pos] = (unsigned long long)(unsigned)(src | (combo << 17))
                   | ((unsigned long long)(unsigned)dst << 32);
    }
    __syncthreads();
    for (int i = tid; i < n_here; i += 256) {
        unsigned long long en = stage[i];
        ebuf[shift[(int)(en >> 32) >> 10] + i] = en;
    }
}

// ---------------------------------------------------------------------------
// csr_build: per-bucket exact CSR + global degree-bin histogram (dcnt).
// ---------------------------------------------------------------------------
__global__ __launch_bounds__(256) void csr_build_kernel(
    const unsigned long long* __restrict__ ebuf, const int* __restrict__ bcur,
    int* __restrict__ cnt, int* __restrict__ off, int* __restrict__ csr_e,
    int* __restrict__ dcnt)
{
    __shared__ int nh[1024];
    __shared__ int cur[1024];
    __shared__ int part[256];
    __shared__ int dloc[NDBIN];

    int b = blockIdx.x;
    int tid = threadIdx.x;
    int nodeBase = b << 10;
    int limit = min(1024, N_NODES - nodeBase);
    int beg = b * BCAP;
    int end = beg + bcur[b];

    for (int i = tid; i < 1024; i += 256) nh[i] = 0;
    if (tid < NDBIN) dloc[tid] = 0;
    __syncthreads();
    for (int i = beg + tid; i < end; i += 256)
        atomicAdd(&nh[(int)(ebuf[i] >> 32) - nodeBase], 1);
    __syncthreads();

    int s0 = nh[tid * 4], s1 = nh[tid * 4 + 1], s2 = nh[tid * 4 + 2], s3 = nh[tid * 4 + 3];
    part[tid] = s0 + s1 + s2 + s3;
    __syncthreads();
    for (int st = 1; st < 256; st <<= 1) {
        int v = 0;
        if (tid >= st) v = part[tid - st];
        __syncthreads();
        if (tid >= st) part[tid] += v;
        __syncthreads();
    }
    int e0 = (tid ? part[tid - 1] : 0);
    int e1 = e0 + s0, e2 = e1 + s1, e3 = e2 + s2;
    cur[tid * 4 + 0] = e0; cur[tid * 4 + 1] = e1;
    cur[tid * 4 + 2] = e2; cur[tid * 4 + 3] = e3;
    int excl[4] = {e0, e1, e2, e3};
    int cval[4] = {s0, s1, s2, s3};
#pragma unroll
    for (int j = 0; j < 4; ++j) {
        int nl = tid * 4 + j;
        if (nl < limit) {
            cnt[nodeBase + nl] = cval[j];
            off[nodeBase + nl] = beg + excl[j];
            atomicAdd(&dloc[min(cval[j], NDBIN - 1)], 1);
        }
    }
    __syncthreads();
    if (tid < NDBIN && dloc[tid]) atomicAdd(&dcnt[tid], dloc[tid]);
    for (int i = beg + tid; i < end; i += 256) {
        unsigned long long en = ebuf[i];
        int pos = atomicAdd(&cur[(int)(en >> 32) - nodeBase], 1);
        csr_e[beg + pos] = (int)(unsigned)en;
    }
}

// dscan: exclusive scan of dcnt -> dbase; init dcur
__global__ __launch_bounds__(64) void dscan_kernel(
    const int* __restrict__ dcnt, int* __restrict__ dbase, int* __restrict__ dcur)
{
    __shared__ int buf[NDBIN];
    int t = threadIdx.x;
    int v = dcnt[t];
    buf[t] = v;
    __syncthreads();
    if (t == 0) {
        int run = 0;
        for (int i = 0; i < NDBIN; ++i) { int c = buf[i]; buf[i] = run; run += c; }
    }
    __syncthreads();
    dbase[t] = buf[t];
    dcur[t] = buf[t];
}

// dperm: scatter nodes into degree-sorted order
__global__ __launch_bounds__(256) void dperm_kernel(
    const int* __restrict__ cnt, int* __restrict__ dcur, int* __restrict__ perm)
{
    int n = blockIdx.x * 256 + threadIdx.x;
    if (n >= N_NODES) return;
    int bin = min(cnt[n], NDBIN - 1);
    int pos = atomicAdd(&dcur[bin], 1);
    perm[pos] = n;
}

// ---------------------------------------------------------------------------
// Gather: 8-lane group per node (via degree-sorted perm); lane = 8 features.
// ---------------------------------------------------------------------------
__global__ __launch_bounds__(256) void gather_kernel(
    const int* __restrict__ cnt, const int* __restrict__ off,
    const int* __restrict__ csr_e, const unsigned short* __restrict__ h,
    const float* __restrict__ comb_l, const float* __restrict__ eps_p,
    const int* __restrict__ perm, unsigned short* __restrict__ zbuf)
{
    const int tid = threadIdx.x;
    const int lane = tid & 63;
    const int grp = lane >> 3;                    // group 0..7 in wave
    const int fo = (lane & 7) << 3;               // 8 features per lane
    const int gidx = blockIdx.x * 32 + (tid >> 6) * 8 + grp;   // N_NODES%32==0
    const int n = perm[gidx];

    const int beg = off[n];
    const int end = beg + cnt[n];

    const f32x2 zero2 = {0.f, 0.f};
    f32x2 a0 = zero2, a1 = zero2, a2 = zero2, a3 = zero2;

#define EDGE_ACC(PK)                                                               \
    {                                                                              \
        int pk_ = (PK);                                                            \
        uint4 hv = *reinterpret_cast<const uint4*>(h + (pk_ & 0x1FFFF) * HID + fo);\
        const float4* ep_ = reinterpret_cast<const float4*>(comb_l + (pk_ >> 17) * HID + fo); \
        float4 e0_ = ep_[0], e1_ = ep_[1];                                         \
        a0 += __builtin_elementwise_max(bfpair(hv.x) + (f32x2){e0_.x, e0_.y}, zero2); \
        a1 += __builtin_elementwise_max(bfpair(hv.y) + (f32x2){e0_.z, e0_.w}, zero2); \
        a2 += __builtin_elementwise_max(bfpair(hv.z) + (f32x2){e1_.x, e1_.y}, zero2); \
        a3 += __builtin_elementwise_max(bfpair(hv.w) + (f32x2){e1_.z, e1_.w}, zero2); \
    }

    int i = beg;
    for (; i + 1 < end; i += 2) {
        int pk0 = csr_e[i];
        int pk1 = csr_e[i + 1];
        EDGE_ACC(pk0);
        EDGE_ACC(pk1);
    }
    if (i < end) EDGE_ACC(csr_e[i]);
#undef EDGE_ACC

    uint4 hn = *reinterpret_cast<const uint4*>(h + (size_t)n * HID + fo);
    float ep1 = 1.0f + eps_p[0];
    f32x2 ep2 = {ep1, ep1};
    f32x2 z0 = __builtin_elementwise_max(ep2 * bfpair(hn.x) + a0, zero2);
    f32x2 z1 = __builtin_elementwise_max(ep2 * bfpair(hn.y) + a1, zero2);
    f32x2 z2 = __builtin_elementwise_max(ep2 * bfpair(hn.z) + a2, zero2);
    f32x2 z3 = __builtin_elementwise_max(ep2 * bfpair(hn.w) + a3, zero2);
    uint4 o;
    o.x = pack2bf(z0.x, z0.y);
    o.y = pack2bf(z1.x, z1.y);
    o.z = pack2bf(z2.x, z2.y);
    o.w = pack2bf(z3.x, z3.y);
    *reinterpret_cast<uint4*>(zbuf + (size_t)n * HID + fo) = o;
}

// ---------------------------------------------------------------------------
// MFMA node MLP, 128-node tiles.
// ---------------------------------------------------------------------------
__global__ __launch_bounds__(256) void mlp_kernel(
    const unsigned short* __restrict__ zbuf, unsigned short* __restrict__ h,
    const unsigned short* __restrict__ w1b, const unsigned short* __restrict__ w2b,
    const float* __restrict__ alpha, const float* __restrict__ beta,
    const float* __restrict__ b2, const int* __restrict__ batch,
    float* __restrict__ out, int out_col, int write_h)
{
    __shared__ unsigned short us[128 * MLP_HID];   // 32 KB
    __shared__ int sbatch[128];

    const int tid = threadIdx.x;
    const int lane = tid & 63;
    const int w = __builtin_amdgcn_readfirstlane(tid >> 6);
    const int base = blockIdx.x * 128;
    const int r16 = lane & 15;
    const int g4 = lane >> 4;                     // 0..3

    if (tid < 128) sbatch[tid] = (base + tid < N_NODES) ? batch[base + tid] : -1;

    bf16x8 awf[2][2];
#pragma unroll
    for (int mo = 0; mo < 2; ++mo)
#pragma unroll
        for (int kt = 0; kt < 2; ++kt) {
            int o = (2 * w + mo) * 16 + r16;
            awf[mo][kt] = *reinterpret_cast<const bf16x8*>(w1b + o * HID + kt * 32 + g4 * 8);
        }
    float4 al[2], be[2];
#pragma unroll
    for (int mo = 0; mo < 2; ++mo) {
        int o0 = (2 * w + mo) * 16 + g4 * 4;
        al[mo] = *reinterpret_cast<const float4*>(alpha + o0);
        be[mo] = *reinterpret_cast<const float4*>(beta + o0);
    }

    char* usb = (char*)us;
#pragma unroll
    for (int nt = 0; nt < 8; ++nt) {
        bf16x8 zf[2];
#pragma unroll
        for (int kt = 0; kt < 2; ++kt)
            zf[kt] = *reinterpret_cast<const bf16x8*>(
                zbuf + (size_t)(base + nt * 16 + r16) * HID + kt * 32 + g4 * 8);
        f32x4 acc[2] = {(f32x4){0.f, 0.f, 0.f, 0.f}, (f32x4){0.f, 0.f, 0.f, 0.f}};
#pragma unroll
        for (int mo = 0; mo < 2; ++mo)
#pragma unroll
            for (int kt = 0; kt < 2; ++kt)
                acc[mo] = __builtin_amdgcn_mfma_f32_16x16x32_bf16(
                    awf[mo][kt], zf[kt], acc[mo], 0, 0, 0);
        int node = nt * 16 + r16;
#pragma unroll
        for (int mo = 0; mo < 2; ++mo) {
            int o0 = (2 * w + mo) * 16 + g4 * 4;
            f32x4 a = acc[mo];
            unsigned lo = pack2bf(fmaxf(a[0] * al[mo].x + be[mo].x, 0.f),
                                  fmaxf(a[1] * al[mo].y + be[mo].y, 0.f));
            unsigned hi = pack2bf(fmaxf(a[2] * al[mo].z + be[mo].z, 0.f),
                                  fmaxf(a[3] * al[mo].w + be[mo].w, 0.f));
            int byte = (node * 256 + o0 * 2) ^ ((node & 7) << 4);
            *reinterpret_cast<uint2*>(usb + byte) = make_uint2(lo, hi);
        }
    }
    __syncthreads();

    bf16x8 b2frag[4];
#pragma unroll
    for (int kt = 0; kt < 4; ++kt)
        b2frag[kt] = *reinterpret_cast<const bf16x8*>(
            w2b + (w * 16 + r16) * MLP_HID + kt * 32 + g4 * 8);

    const int o = w * 16 + r16;
    const float bias = b2[o];
    int gprev = -2;
    float run = 0.f;
#pragma unroll
    for (int mt = 0; mt < 8; ++mt) {
        f32x4 acc2 = (f32x4){0.f, 0.f, 0.f, 0.f};
#pragma unroll
        for (int kt = 0; kt < 4; ++kt) {
            int node = mt * 16 + r16;
            int byte = (node * 256 + (kt * 32 + g4 * 8) * 2) ^ ((node & 7) << 4);
            bf16x8 af = *reinterpret_cast<const bf16x8*>(usb + byte);
            acc2 = __builtin_amdgcn_mfma_f32_16x16x32_bf16(af, b2frag[kt], acc2, 0, 0, 0);
        }
#pragma unroll
        for (int r = 0; r < 4; ++r) {
            int node = mt * 16 + g4 * 4 + r;
            int gn = base + node;
            float v = fmaxf(acc2[r] + bias, 0.f);
            if (write_h && gn < N_NODES) h[(size_t)gn * HID + o] = f2bf(v);
            int gb = sbatch[node];
            if (gb != gprev) {
                if (gprev >= 0) atomicAdd(&out[gprev * 256 + out_col + o], run);
                run = 0.f;
                gprev = gb;
            }
            if (gb >= 0) run += v;
        }
    }
    if (gprev >= 0) atomicAdd(&out[gprev * 256 + out_col + o], run);
}

// ---------------------------------------------------------------------------
extern "C" void kernel_launch(void* const* d_in, const int* in_sizes, int n_in,
                              void* d_out, int out_size, void* d_ws, size_t ws_size,
                              hipStream_t stream)
{
    const int*   x        = (const int*)d_in[0];
    const int*   ei       = (const int*)d_in[1];
    const int*   ea       = (const int*)d_in[2];
    const int*   batch    = (const int*)d_in[3];
    const float* atom_emb = (const float*)d_in[4];
    const float* edge_emb = (const float*)d_in[5];
    const float* w1       = (const float*)d_in[6];
    const float* b1       = (const float*)d_in[7];
    const float* bn_g     = (const float*)d_in[8];
    const float* bn_b     = (const float*)d_in[9];
    const float* bn_m     = (const float*)d_in[10];
    const float* bn_v     = (const float*)d_in[11];
    const float* w2       = (const float*)d_in[12];
    const float* b2       = (const float*)d_in[13];
    const float* eps      = (const float*)d_in[14];

    float* out = (float*)d_out;

    // workspace layout (all chunks 16B-aligned)
    const size_t NODE_PAD = 100096;
    char* ws = (char*)d_ws;
    unsigned short* h     = (unsigned short*)ws; ws += NODE_PAD * HID * 2;            // 12.8 MB
    unsigned short* zbuf  = (unsigned short*)ws; ws += NODE_PAD * HID * 2;            // 12.8 MB
    float* comb           = (float*)ws;          ws += (size_t)3 * N_COMBO * HID * 4; // 203 KB
    unsigned short* w1b   = (unsigned short*)ws; ws += (size_t)3 * MLP_HID * HID * 2;
    unsigned short* w2b   = (unsigned short*)ws; ws += (size_t)3 * HID * MLP_HID * 2;
    float* alpha          = (float*)ws;          ws += (size_t)3 * MLP_HID * 4;
    float* betab          = (float*)ws;          ws += (size_t)3 * MLP_HID * 4;
    int*   cnt            = (int*)ws;            ws += (size_t)N_NODES * 4;
    int*   off            = (int*)ws;            ws += (size_t)N_NODES * 4;
    int*   perm           = (int*)ws;            ws += (size_t)N_NODES * 4;
    int*   bcur           = (int*)ws;            ws += 128 * 4;
    int*   dcnt           = (int*)ws;            ws += NDBIN * 4;
    int*   dbase          = (int*)ws;            ws += NDBIN * 4;
    int*   dcur           = (int*)ws;            ws += NDBIN * 4;
    unsigned long long* ebuf = (unsigned long long*)ws; ws += (size_t)NBUCK * BCAP * 8; // 16.1 MB
    int*   csr_e          = (int*)ws;            ws += (size_t)NBUCK * BCAP * 4;      // 8.0 MB

    const int nblk128 = (N_NODES + 127) / 128;   // 782

    hipMemsetAsync(out, 0, (size_t)N_GRAPHS * 256 * sizeof(float), stream);
    hipMemsetAsync(bcur, 0, (128 + NDBIN) * sizeof(int), stream);   // bcur + dcnt

    misc_kernel<<<NB_EMBED + NB_PREP, 256, 0, stream>>>(
        x, atom_emb, batch, h, out,
        edge_emb, w1, w2, b1, bn_g, bn_b, bn_m, bn_v,
        comb, w1b, w2b, alpha, betab);

    bscatter_kernel<<<(N_EDGES + CHUNK - 1) / CHUNK, 256, 0, stream>>>(ei, ea, bcur, ebuf);
    csr_build_kernel<<<NBUCK, 256, 0, stream>>>(ebuf, bcur, cnt, off, csr_e, dcnt);
    dscan_kernel<<<1, NDBIN, 0, stream>>>(dcnt, dbase, dcur);
    dperm_kernel<<<(N_NODES + 255) / 256, 256, 0, stream>>>(cnt, dcur, perm);

    for (int l = 0; l < 3; ++l) {
        gather_kernel<<<N_NODES / 32, 256, 0, stream>>>(
            cnt, off, csr_e, h, comb + (size_t)l * N_COMBO * HID, eps + l, perm, zbuf);
        mlp_kernel<<<nblk128, 256, 0, stream>>>(
            zbuf, h,
            w1b + (size_t)l * MLP_HID * HID, w2b + (size_t)l * HID * MLP_HID,
            alpha + (size_t)l * MLP_HID, betab + (size_t)l * MLP_HID,
            b2 + (size_t)l * HID, batch, out, (l + 1) * HID, (l < 2) ? 1 : 0);
    }
}

// Round 15
// 318.282 us; speedup vs baseline: 1.7289x; 1.7289x over previous
//
#include <hip/hip_runtime.h>

#define N_NODES 100000
#define N_EDGES 1600000
#define N_GRAPHS 1024
#define HID 64
#define MLP_HID 128
#define N_COMBO 264    // 22*6*2 edge-attr combinations
#define NBUCK 98       // ceil(N_NODES / 1024)
#define BCAP 20480     // fixed bucket capacity (mean 16384)
#define CHUNK 6144     // edges per bscatter block (48KB LDS staging)
#define NDBIN 64       // degree bins for in-bucket counting sort

#define NB_EMBED 1563  // (N_NODES+63)/64
#define NPREP (3*N_COMBO*HID + 3*MLP_HID*HID + 3*MLP_HID)   // 75648
#define NB_PREP 296    // ceil(NPREP/256)

typedef __attribute__((ext_vector_type(8))) short bf16x8;
typedef __attribute__((ext_vector_type(4))) float f32x4;
typedef __attribute__((ext_vector_type(2))) float f32x2;

static __device__ __forceinline__ float bf2f(unsigned short u) {
    union { unsigned int i; float f; } v; v.i = ((unsigned int)u) << 16; return v.f;
}
static __device__ __forceinline__ unsigned short f2bf(float f) {
    union { float f; unsigned int i; } v; v.f = f;
    unsigned int u = v.i;
    unsigned int r = u + 0x7FFFu + ((u >> 16) & 1u);   // RNE
    return (unsigned short)(r >> 16);
}
static __device__ __forceinline__ f32x2 bfpair(unsigned int u) {
    union { unsigned int i; float f; } lo, hi;
    lo.i = u << 16;
    hi.i = u & 0xFFFF0000u;
    f32x2 r; r.x = lo.f; r.y = hi.f; return r;
}
static __device__ __forceinline__ unsigned int pack2bf(float a, float b) {
    return (unsigned int)f2bf(a) | ((unsigned int)f2bf(b) << 16);
}

// ---------------------------------------------------------------------------
// Fused misc kernel: [0,NB_EMBED) atom-embed + pooled[0];
//                    [NB_EMBED, +NB_PREP) weight/comb prep.
// ---------------------------------------------------------------------------
__global__ __launch_bounds__(256) void misc_kernel(
    const int* __restrict__ x, const float* __restrict__ atom_emb,
    const int* __restrict__ batch, unsigned short* __restrict__ h,
    float* __restrict__ out,
    const float* __restrict__ edge_emb,
    const float* __restrict__ w1, const float* __restrict__ w2,
    const float* __restrict__ b1, const float* __restrict__ bn_g,
    const float* __restrict__ bn_b, const float* __restrict__ bn_m,
    const float* __restrict__ bn_v,
    float* __restrict__ comb,
    unsigned short* __restrict__ w1b, unsigned short* __restrict__ w2b,
    float* __restrict__ alpha, float* __restrict__ beta)
{
    const int bid = blockIdx.x;
    const int tid = threadIdx.x;

    if (bid < NB_EMBED) {
        int f = tid & 63;
        int q = __builtin_amdgcn_readfirstlane(tid >> 6);   // wave-uniform
        int base = bid * 64 + q * 16;
        float run = 0.f;
        int cg = -1;
        for (int k = 0; k < 16; ++k) {
            int gn = base + k;
            if (gn >= N_NODES) break;
            const int* xp = x + gn * 9;                     // uniform -> s_load
            float acc = 0.f;
#pragma unroll
            for (int j = 0; j < 9; ++j) {
                int idx = xp[j];
                acc += atom_emb[(j * 119 + idx) * HID + f]; // coalesced 256B
            }
            h[(size_t)gn * HID + f] = f2bf(acc);
            int g = batch[gn];                              // uniform
            if (g != cg) {
                if (cg >= 0) atomicAdd(&out[cg * 256 + f], run);
                run = 0.f; cg = g;
            }
            run += acc;
        }
        if (cg >= 0) atomicAdd(&out[cg * 256 + f], run);
    } else {
        int t = (bid - NB_EMBED) * 256 + tid;
        const int NC = 3 * N_COMBO * HID;   // 50688
        const int NW = 3 * MLP_HID * HID;   // 24576
        if (t < NC) {
            int d = t & 63;
            int c = (t >> 6) % N_COMBO;
            int l = (t >> 6) / N_COMBO;
            int a0 = c / 12, r = c % 12, a1 = r >> 1, a2 = r & 1;
            const float* base = edge_emb + (size_t)l * 3 * 22 * HID;
            comb[t] = base[(0 * 22 + a0) * HID + d]
                    + base[(1 * 22 + a1) * HID + d]
                    + base[(2 * 22 + a2) * HID + d];
        } else if (t < NC + NW) {
            int i = t - NC;
            w1b[i] = f2bf(w1[i]);
            w2b[i] = f2bf(w2[i]);
        } else if (t < NC + NW + 3 * MLP_HID) {
            int i = t - NC - NW;
            float a = rsqrtf(bn_v[i] + 1e-5f) * bn_g[i];
            alpha[i] = a;
            beta[i] = (b1[i] - bn_m[i]) * a + bn_b[i];
        }
    }
}

// ---------------------------------------------------------------------------
// bscatter: LDS-staged reorder by bucket into fixed-capacity regions.
// ---------------------------------------------------------------------------
__global__ __launch_bounds__(256) void bscatter_kernel(
    const int* __restrict__ ei, const int* __restrict__ ea,
    int* __restrict__ bcur, unsigned long long* __restrict__ ebuf)
{
    __shared__ unsigned long long stage[CHUNK];   // 48 KB
    __shared__ int hist[NBUCK];
    __shared__ int lbase[NBUCK];
    __shared__ int shift[NBUCK];
    __shared__ int sbuf[128];

    int tid = threadIdx.x;
    int base = blockIdx.x * CHUNK;
    int n_here = min(CHUNK, N_EDGES - base);

    for (int i = tid; i < NBUCK; i += 256) hist[i] = 0;
    __syncthreads();
    for (int i = tid; i < n_here; i += 256)
        atomicAdd(&hist[ei[N_EDGES + base + i] >> 10], 1);
    __syncthreads();
    if (tid < 128) sbuf[tid] = (tid < NBUCK) ? hist[tid] : 0;
    __syncthreads();
    for (int s = 1; s < 128; s <<= 1) {
        int u = 0;
        if (tid < 128 && tid >= s) u = sbuf[tid - s];
        __syncthreads();
        if (tid < 128) sbuf[tid] += u;
        __syncthreads();
    }
    if (tid < NBUCK) lbase[tid] = sbuf[tid] - hist[tid];
    __syncthreads();
    if (tid < NBUCK) {
        int c = hist[tid];
        if (c > 0) {
            int g = tid * BCAP + atomicAdd(&bcur[tid], c);
            shift[tid] = g - lbase[tid];
        }
        hist[tid] = lbase[tid];
    }
    __syncthreads();
    for (int i = tid; i < n_here; i += 256) {
        int e = base + i;
        int src = ei[e];
        int dst = ei[N_EDGES + e];
        int combo = (ea[e * 3 + 0] * 6 + ea[e * 3 + 1]) * 2 + ea[e * 3 + 2];
        int pos = atomicAdd(&hist[dst >> 10], 1);
        stage[pos] = (unsigned long long)(unsigned)(src | (combo << 17))
                   | ((unsigned long long)(unsigned)dst << 32);
    }
    __syncthreads();
    for (int i = tid; i < n_here; i += 256) {
        unsigned long long en = stage[i];
        ebuf[shift[(int)(en >> 32) >> 10] + i] = en;
    }
}

// ---------------------------------------------------------------------------
// csr_build: per-bucket exact CSR + in-bucket degree counting-sort -> perm.
// All sorting state is LDS-local; no global atomics.
// ---------------------------------------------------------------------------
__global__ __launch_bounds__(256) void csr_build_kernel(
    const unsigned long long* __restrict__ ebuf, const int* __restrict__ bcur,
    int* __restrict__ cnt, int* __restrict__ off, int* __restrict__ csr_e,
    int* __restrict__ perm)
{
    __shared__ int nh[1024];
    __shared__ int cur[1024];
    __shared__ int part[256];
    __shared__ int dbin[NDBIN];   // degree-bin histogram -> cursors

    int b = blockIdx.x;
    int tid = threadIdx.x;
    int nodeBase = b << 10;
    int limit = min(1024, N_NODES - nodeBase);
    int beg = b * BCAP;
    int end = beg + bcur[b];

    for (int i = tid; i < 1024; i += 256) nh[i] = 0;
    if (tid < NDBIN) dbin[tid] = 0;
    __syncthreads();
    for (int i = beg + tid; i < end; i += 256)
        atomicAdd(&nh[(int)(ebuf[i] >> 32) - nodeBase], 1);
    __syncthreads();

    int s0 = nh[tid * 4], s1 = nh[tid * 4 + 1], s2 = nh[tid * 4 + 2], s3 = nh[tid * 4 + 3];
    part[tid] = s0 + s1 + s2 + s3;
    __syncthreads();
    for (int st = 1; st < 256; st <<= 1) {
        int v = 0;
        if (tid >= st) v = part[tid - st];
        __syncthreads();
        if (tid >= st) part[tid] += v;
        __syncthreads();
    }
    int e0 = (tid ? part[tid - 1] : 0);
    int e1 = e0 + s0, e2 = e1 + s1, e3 = e2 + s2;
    cur[tid * 4 + 0] = e0; cur[tid * 4 + 1] = e1;
    cur[tid * 4 + 2] = e2; cur[tid * 4 + 3] = e3;
    int excl[4] = {e0, e1, e2, e3};
    int cval[4] = {s0, s1, s2, s3};
#pragma unroll
    for (int j = 0; j < 4; ++j) {
        int nl = tid * 4 + j;
        if (nl < limit) {
            cnt[nodeBase + nl] = cval[j];
            off[nodeBase + nl] = beg + excl[j];
            atomicAdd(&dbin[min(cval[j], NDBIN - 1)], 1);   // LDS histogram
        }
    }
    __syncthreads();
    // exclusive scan of dbin (serial, 64 elems) -> bin cursors
    if (tid == 0) {
        int run = 0;
        for (int i = 0; i < NDBIN; ++i) { int c = dbin[i]; dbin[i] = run; run += c; }
    }
    __syncthreads();
    // counting-sort rank -> perm (degree-sorted within bucket)
#pragma unroll
    for (int j = 0; j < 4; ++j) {
        int nl = tid * 4 + j;
        if (nl < limit) {
            int rank = atomicAdd(&dbin[min(cval[j], NDBIN - 1)], 1);
            perm[nodeBase + rank] = nodeBase + nl;
        }
    }
    // CSR placement
    for (int i = beg + tid; i < end; i += 256) {
        unsigned long long en = ebuf[i];
        int pos = atomicAdd(&cur[(int)(en >> 32) - nodeBase], 1);
        csr_e[beg + pos] = (int)(unsigned)en;
    }
}

// ---------------------------------------------------------------------------
// Gather: 8-lane group per node (via degree-sorted perm); lane = 8 features.
// ---------------------------------------------------------------------------
__global__ __launch_bounds__(256) void gather_kernel(
    const int* __restrict__ cnt, const int* __restrict__ off,
    const int* __restrict__ csr_e, const unsigned short* __restrict__ h,
    const float* __restrict__ comb_l, const float* __restrict__ eps_p,
    const int* __restrict__ perm, unsigned short* __restrict__ zbuf)
{
    const int tid = threadIdx.x;
    const int lane = tid & 63;
    const int grp = lane >> 3;                    // group 0..7 in wave
    const int fo = (lane & 7) << 3;               // 8 features per lane
    const int gidx = blockIdx.x * 32 + (tid >> 6) * 8 + grp;   // N_NODES%32==0
    const int n = perm[gidx];

    const int beg = off[n];
    const int end = beg + cnt[n];

    const f32x2 zero2 = {0.f, 0.f};
    f32x2 a0 = zero2, a1 = zero2, a2 = zero2, a3 = zero2;

#define EDGE_ACC(PK)                                                               \
    {                                                                              \
        int pk_ = (PK);                                                            \
        uint4 hv = *reinterpret_cast<const uint4*>(h + (pk_ & 0x1FFFF) * HID + fo);\
        const float4* ep_ = reinterpret_cast<const float4*>(comb_l + (pk_ >> 17) * HID + fo); \
        float4 e0_ = ep_[0], e1_ = ep_[1];                                         \
        a0 += __builtin_elementwise_max(bfpair(hv.x) + (f32x2){e0_.x, e0_.y}, zero2); \
        a1 += __builtin_elementwise_max(bfpair(hv.y) + (f32x2){e0_.z, e0_.w}, zero2); \
        a2 += __builtin_elementwise_max(bfpair(hv.z) + (f32x2){e1_.x, e1_.y}, zero2); \
        a3 += __builtin_elementwise_max(bfpair(hv.w) + (f32x2){e1_.z, e1_.w}, zero2); \
    }

    int i = beg;
    for (; i + 1 < end; i += 2) {
        int pk0 = csr_e[i];
        int pk1 = csr_e[i + 1];
        EDGE_ACC(pk0);
        EDGE_ACC(pk1);
    }
    if (i < end) EDGE_ACC(csr_e[i]);
#undef EDGE_ACC

    uint4 hn = *reinterpret_cast<const uint4*>(h + (size_t)n * HID + fo);
    float ep1 = 1.0f + eps_p[0];
    f32x2 ep2 = {ep1, ep1};
    f32x2 z0 = __builtin_elementwise_max(ep2 * bfpair(hn.x) + a0, zero2);
    f32x2 z1 = __builtin_elementwise_max(ep2 * bfpair(hn.y) + a1, zero2);
    f32x2 z2 = __builtin_elementwise_max(ep2 * bfpair(hn.z) + a2, zero2);
    f32x2 z3 = __builtin_elementwise_max(ep2 * bfpair(hn.w) + a3, zero2);
    uint4 o;
    o.x = pack2bf(z0.x, z0.y);
    o.y = pack2bf(z1.x, z1.y);
    o.z = pack2bf(z2.x, z2.y);
    o.w = pack2bf(z3.x, z3.y);
    *reinterpret_cast<uint4*>(zbuf + (size_t)n * HID + fo) = o;
}

// ---------------------------------------------------------------------------
// MFMA node MLP, 128-node tiles.
// ---------------------------------------------------------------------------
__global__ __launch_bounds__(256) void mlp_kernel(
    const unsigned short* __restrict__ zbuf, unsigned short* __restrict__ h,
    const unsigned short* __restrict__ w1b, const unsigned short* __restrict__ w2b,
    const float* __restrict__ alpha, const float* __restrict__ beta,
    const float* __restrict__ b2, const int* __restrict__ batch,
    float* __restrict__ out, int out_col, int write_h)
{
    __shared__ unsigned short us[128 * MLP_HID];   // 32 KB
    __shared__ int sbatch[128];

    const int tid = threadIdx.x;
    const int lane = tid & 63;
    const int w = __builtin_amdgcn_readfirstlane(tid >> 6);
    const int base = blockIdx.x * 128;
    const int r16 = lane & 15;
    const int g4 = lane >> 4;                     // 0..3

    if (tid < 128) sbatch[tid] = (base + tid < N_NODES) ? batch[base + tid] : -1;

    bf16x8 awf[2][2];
#pragma unroll
    for (int mo = 0; mo < 2; ++mo)
#pragma unroll
        for (int kt = 0; kt < 2; ++kt) {
            int o = (2 * w + mo) * 16 + r16;
            awf[mo][kt] = *reinterpret_cast<const bf16x8*>(w1b + o * HID + kt * 32 + g4 * 8);
        }
    float4 al[2], be[2];
#pragma unroll
    for (int mo = 0; mo < 2; ++mo) {
        int o0 = (2 * w + mo) * 16 + g4 * 4;
        al[mo] = *reinterpret_cast<const float4*>(alpha + o0);
        be[mo] = *reinterpret_cast<const float4*>(beta + o0);
    }

    char* usb = (char*)us;
#pragma unroll
    for (int nt = 0; nt < 8; ++nt) {
        bf16x8 zf[2];
#pragma unroll
        for (int kt = 0; kt < 2; ++kt)
            zf[kt] = *reinterpret_cast<const bf16x8*>(
                zbuf + (size_t)(base + nt * 16 + r16) * HID + kt * 32 + g4 * 8);
        f32x4 acc[2] = {(f32x4){0.f, 0.f, 0.f, 0.f}, (f32x4){0.f, 0.f, 0.f, 0.f}};
#pragma unroll
        for (int mo = 0; mo < 2; ++mo)
#pragma unroll
            for (int kt = 0; kt < 2; ++kt)
                acc[mo] = __builtin_amdgcn_mfma_f32_16x16x32_bf16(
                    awf[mo][kt], zf[kt], acc[mo], 0, 0, 0);
        int node = nt * 16 + r16;
#pragma unroll
        for (int mo = 0; mo < 2; ++mo) {
            int o0 = (2 * w + mo) * 16 + g4 * 4;
            f32x4 a = acc[mo];
            unsigned lo = pack2bf(fmaxf(a[0] * al[mo].x + be[mo].x, 0.f),
                                  fmaxf(a[1] * al[mo].y + be[mo].y, 0.f));
            unsigned hi = pack2bf(fmaxf(a[2] * al[mo].z + be[mo].z, 0.f),
                                  fmaxf(a[3] * al[mo].w + be[mo].w, 0.f));
            int byte = (node * 256 + o0 * 2) ^ ((node & 7) << 4);
            *reinterpret_cast<uint2*>(usb + byte) = make_uint2(lo, hi);
        }
    }
    __syncthreads();

    bf16x8 b2frag[4];
#pragma unroll
    for (int kt = 0; kt < 4; ++kt)
        b2frag[kt] = *reinterpret_cast<const bf16x8*>(
            w2b + (w * 16 + r16) * MLP_HID + kt * 32 + g4 * 8);

    const int o = w * 16 + r16;
    const float bias = b2[o];
    int gprev = -2;
    float run = 0.f;
#pragma unroll
    for (int mt = 0; mt < 8; ++mt) {
        f32x4 acc2 = (f32x4){0.f, 0.f, 0.f, 0.f};
#pragma unroll
        for (int kt = 0; kt < 4; ++kt) {
            int node = mt * 16 + r16;
            int byte = (node * 256 + (kt * 32 + g4 * 8) * 2) ^ ((node & 7) << 4);
            bf16x8 af = *reinterpret_cast<const bf16x8*>(usb + byte);
            acc2 = __builtin_amdgcn_mfma_f32_16x16x32_bf16(af, b2frag[kt], acc2, 0, 0, 0);
        }
#pragma unroll
        for (int r = 0; r < 4; ++r) {
            int node = mt * 16 + g4 * 4 + r;
            int gn = base + node;
            float v = fmaxf(acc2[r] + bias, 0.f);
            if (write_h && gn < N_NODES) h[(size_t)gn * HID + o] = f2bf(v);
            int gb = sbatch[node];
            if (gb != gprev) {
                if (gprev >= 0) atomicAdd(&out[gprev * 256 + out_col + o], run);
                run = 0.f;
                gprev = gb;
            }
            if (gb >= 0) run += v;
        }
    }
    if (gprev >= 0) atomicAdd(&out[gprev * 256 + out_col + o], run);
}

// ---------------------------------------------------------------------------
extern "C" void kernel_launch(void* const* d_in, const int* in_sizes, int n_in,
                              void* d_out, int out_size, void* d_ws, size_t ws_size,
                              hipStream_t stream)
{
    const int*   x        = (const int*)d_in[0];
    const int*   ei       = (const int*)d_in[1];
    const int*   ea       = (const int*)d_in[2];
    const int*   batch    = (const int*)d_in[3];
    const float* atom_emb = (const float*)d_in[4];
    const float* edge_emb = (const float*)d_in[5];
    const float* w1       = (const float*)d_in[6];
    const float* b1       = (const float*)d_in[7];
    const float* bn_g     = (const float*)d_in[8];
    const float* bn_b     = (const float*)d_in[9];
    const float* bn_m     = (const float*)d_in[10];
    const float* bn_v     = (const float*)d_in[11];
    const float* w2       = (const float*)d_in[12];
    const float* b2       = (const float*)d_in[13];
    const float* eps      = (const float*)d_in[14];

    float* out = (float*)d_out;

    // workspace layout (all chunks 16B-aligned)
    const size_t NODE_PAD = 100096;
    char* ws = (char*)d_ws;
    unsigned short* h     = (unsigned short*)ws; ws += NODE_PAD * HID * 2;            // 12.8 MB
    unsigned short* zbuf  = (unsigned short*)ws; ws += NODE_PAD * HID * 2;            // 12.8 MB
    float* comb           = (float*)ws;          ws += (size_t)3 * N_COMBO * HID * 4; // 203 KB
    unsigned short* w1b   = (unsigned short*)ws; ws += (size_t)3 * MLP_HID * HID * 2;
    unsigned short* w2b   = (unsigned short*)ws; ws += (size_t)3 * HID * MLP_HID * 2;
    float* alpha          = (float*)ws;          ws += (size_t)3 * MLP_HID * 4;
    float* betab          = (float*)ws;          ws += (size_t)3 * MLP_HID * 4;
    int*   cnt            = (int*)ws;            ws += (size_t)N_NODES * 4;
    int*   off            = (int*)ws;            ws += (size_t)N_NODES * 4;
    int*   perm           = (int*)ws;            ws += (size_t)N_NODES * 4;
    int*   bcur           = (int*)ws;            ws += 128 * 4;
    unsigned long long* ebuf = (unsigned long long*)ws; ws += (size_t)NBUCK * BCAP * 8; // 16.1 MB
    int*   csr_e          = (int*)ws;            ws += (size_t)NBUCK * BCAP * 4;      // 8.0 MB

    const int nblk128 = (N_NODES + 127) / 128;   // 782

    hipMemsetAsync(out, 0, (size_t)N_GRAPHS * 256 * sizeof(float), stream);
    hipMemsetAsync(bcur, 0, 128 * sizeof(int), stream);

    misc_kernel<<<NB_EMBED + NB_PREP, 256, 0, stream>>>(
        x, atom_emb, batch, h, out,
        edge_emb, w1, w2, b1, bn_g, bn_b, bn_m, bn_v,
        comb, w1b, w2b, alpha, betab);

    bscatter_kernel<<<(N_EDGES + CHUNK - 1) / CHUNK, 256, 0, stream>>>(ei, ea, bcur, ebuf);
    csr_build_kernel<<<NBUCK, 256, 0, stream>>>(ebuf, bcur, cnt, off, csr_e, perm);

    for (int l = 0; l < 3; ++l) {
        gather_kernel<<<N_NODES / 32, 256, 0, stream>>>(
            cnt, off, csr_e, h, comb + (size_t)l * N_COMBO * HID, eps + l, perm, zbuf);
        mlp_kernel<<<nblk128, 256, 0, stream>>>(
            zbuf, h,
            w1b + (size_t)l * MLP_HID * HID, w2b + (size_t)l * HID * MLP_HID,
            alpha + (size_t)l * MLP_HID, betab + (size_t)l * MLP_HID,
            b2 + (size_t)l * HID, batch, out, (l + 1) * HID, (l < 2) ? 1 : 0);
    }
}

// Round 16
// 286.463 us; speedup vs baseline: 1.9210x; 1.1111x over previous
//
#include <hip/hip_runtime.h>

#define N_NODES 100000
#define N_EDGES 1600000
#define N_GRAPHS 1024
#define HID 64
#define MLP_HID 128
#define N_COMBO 264    // 22*6*2 edge-attr combinations
#define NBUCK 98       // ceil(N_NODES / 1024)
#define BCAP 20480     // fixed bucket capacity (mean 16384)
#define CHUNK 6144     // edges per bscatter block (48KB LDS staging)

#define NB_EMBED 1563  // (N_NODES+63)/64
#define NPREP (3*N_COMBO*HID + 3*MLP_HID*HID + 3*MLP_HID)   // 75648
#define NB_PREP 296    // ceil(NPREP/256)

typedef __attribute__((ext_vector_type(8))) short bf16x8;
typedef __attribute__((ext_vector_type(4))) float f32x4;
typedef __attribute__((ext_vector_type(2))) float f32x2;

static __device__ __forceinline__ float bf2f(unsigned short u) {
    union { unsigned int i; float f; } v; v.i = ((unsigned int)u) << 16; return v.f;
}
static __device__ __forceinline__ unsigned short f2bf(float f) {
    union { float f; unsigned int i; } v; v.f = f;
    unsigned int u = v.i;
    unsigned int r = u + 0x7FFFu + ((u >> 16) & 1u);   // RNE
    return (unsigned short)(r >> 16);
}
static __device__ __forceinline__ f32x2 bfpair(unsigned int u) {
    union { unsigned int i; float f; } lo, hi;
    lo.i = u << 16;
    hi.i = u & 0xFFFF0000u;
    f32x2 r; r.x = lo.f; r.y = hi.f; return r;
}
static __device__ __forceinline__ unsigned int pack2bf(float a, float b) {
    return (unsigned int)f2bf(a) | ((unsigned int)f2bf(b) << 16);
}

// ---------------------------------------------------------------------------
// Fused misc kernel: [0,NB_EMBED) atom-embed + pooled[0];
//                    [NB_EMBED, +NB_PREP) weight/comb prep;
//                    last block: zero bcur.
// ---------------------------------------------------------------------------
__global__ __launch_bounds__(256) void misc_kernel(
    const int* __restrict__ x, const float* __restrict__ atom_emb,
    const int* __restrict__ batch, unsigned short* __restrict__ h,
    float* __restrict__ out,
    const float* __restrict__ edge_emb,
    const float* __restrict__ w1, const float* __restrict__ w2,
    const float* __restrict__ b1, const float* __restrict__ bn_g,
    const float* __restrict__ bn_b, const float* __restrict__ bn_m,
    const float* __restrict__ bn_v,
    float* __restrict__ comb,
    unsigned short* __restrict__ w1b, unsigned short* __restrict__ w2b,
    float* __restrict__ alpha, float* __restrict__ beta,
    int* __restrict__ bcur)
{
    const int bid = blockIdx.x;
    const int tid = threadIdx.x;

    if (bid < NB_EMBED) {
        int f = tid & 63;
        int q = __builtin_amdgcn_readfirstlane(tid >> 6);   // wave-uniform
        int base = bid * 64 + q * 16;
        float run = 0.f;
        int cg = -1;
        for (int k = 0; k < 16; ++k) {
            int gn = base + k;
            if (gn >= N_NODES) break;
            const int* xp = x + gn * 9;                     // uniform -> s_load
            float acc = 0.f;
#pragma unroll
            for (int j = 0; j < 9; ++j) {
                int idx = xp[j];
                acc += atom_emb[(j * 119 + idx) * HID + f]; // coalesced 256B
            }
            h[(size_t)gn * HID + f] = f2bf(acc);
            int g = batch[gn];                              // uniform
            if (g != cg) {
                if (cg >= 0) atomicAdd(&out[cg * 256 + f], run);
                run = 0.f; cg = g;
            }
            run += acc;
        }
        if (cg >= 0) atomicAdd(&out[cg * 256 + f], run);
    } else if (bid < NB_EMBED + NB_PREP) {
        int t = (bid - NB_EMBED) * 256 + tid;
        const int NC = 3 * N_COMBO * HID;   // 50688
        const int NW = 3 * MLP_HID * HID;   // 24576
        if (t < NC) {
            int d = t & 63;
            int c = (t >> 6) % N_COMBO;
            int l = (t >> 6) / N_COMBO;
            int a0 = c / 12, r = c % 12, a1 = r >> 1, a2 = r & 1;
            const float* base = edge_emb + (size_t)l * 3 * 22 * HID;
            comb[t] = base[(0 * 22 + a0) * HID + d]
                    + base[(1 * 22 + a1) * HID + d]
                    + base[(2 * 22 + a2) * HID + d];
        } else if (t < NC + NW) {
            int i = t - NC;
            w1b[i] = f2bf(w1[i]);
            w2b[i] = f2bf(w2[i]);
        } else if (t < NC + NW + 3 * MLP_HID) {
            int i = t - NC - NW;
            float a = rsqrtf(bn_v[i] + 1e-5f) * bn_g[i];
            alpha[i] = a;
            beta[i] = (b1[i] - bn_m[i]) * a + bn_b[i];
        }
    } else {
        if (tid < 128) bcur[tid] = 0;
    }
}

// ---------------------------------------------------------------------------
// bscatter: LDS-staged reorder by bucket into fixed-capacity regions.
// edge record = (src | combo<<17) | dst<<32  (as u64)
// ---------------------------------------------------------------------------
__global__ __launch_bounds__(256) void bscatter_kernel(
    const int* __restrict__ ei, const int* __restrict__ ea,
    int* __restrict__ bcur, unsigned long long* __restrict__ ebuf)
{
    __shared__ unsigned long long stage[CHUNK];   // 48 KB
    __shared__ int hist[NBUCK];
    __shared__ int lbase[NBUCK];
    __shared__ int shift[NBUCK];
    __shared__ int sbuf[128];

    int tid = threadIdx.x;
    int base = blockIdx.x * CHUNK;
    int n_here = min(CHUNK, N_EDGES - base);

    for (int i = tid; i < NBUCK; i += 256) hist[i] = 0;
    __syncthreads();
    for (int i = tid; i < n_here; i += 256)
        atomicAdd(&hist[ei[N_EDGES + base + i] >> 10], 1);
    __syncthreads();
    if (tid < 128) sbuf[tid] = (tid < NBUCK) ? hist[tid] : 0;
    __syncthreads();
    for (int s = 1; s < 128; s <<= 1) {
        int u = 0;
        if (tid < 128 && tid >= s) u = sbuf[tid - s];
        __syncthreads();
        if (tid < 128) sbuf[tid] += u;
        __syncthreads();
    }
    if (tid < NBUCK) lbase[tid] = sbuf[tid] - hist[tid];
    __syncthreads();
    if (tid < NBUCK) {
        int c = hist[tid];
        if (c > 0) {
            int g = tid * BCAP + atomicAdd(&bcur[tid], c);
            shift[tid] = g - lbase[tid];
        }
        hist[tid] = lbase[tid];
    }
    __syncthreads();
    for (int i = tid; i < n_here; i += 256) {
        int e = base + i;
        int src = ei[e];
        int dst = ei[N_EDGES + e];
        int combo = (ea[e * 3 + 0] * 6 + ea[e * 3 + 1]) * 2 + ea[e * 3 + 2];
        int pos = atomicAdd(&hist[dst >> 10], 1);
        stage[pos] = (unsigned long long)(unsigned)(src | (combo << 17))
                   | ((unsigned long long)(unsigned)dst << 32);
    }
    __syncthreads();
    for (int i = tid; i < n_here; i += 256) {
        unsigned long long en = stage[i];
        ebuf[shift[(int)(en >> 32) >> 10] + i] = en;
    }
}

// ---------------------------------------------------------------------------
// csr_build: one block per bucket; exact per-node CSR within the bucket's
// region [b*BCAP, b*BCAP + bcur[b]); writes global cnt/off.
// ---------------------------------------------------------------------------
__global__ __launch_bounds__(256) void csr_build_kernel(
    const unsigned long long* __restrict__ ebuf, const int* __restrict__ bcur,
    int* __restrict__ cnt, int* __restrict__ off, int* __restrict__ csr_e)
{
    __shared__ int nh[1024];
    __shared__ int cur[1024];
    __shared__ int part[256];

    int b = blockIdx.x;
    int tid = threadIdx.x;
    int nodeBase = b << 10;
    int limit = min(1024, N_NODES - nodeBase);
    int beg = b * BCAP;
    int end = beg + bcur[b];

    for (int i = tid; i < 1024; i += 256) nh[i] = 0;
    __syncthreads();
    for (int i = beg + tid; i < end; i += 256)
        atomicAdd(&nh[(int)(ebuf[i] >> 32) - nodeBase], 1);
    __syncthreads();

    int s0 = nh[tid * 4], s1 = nh[tid * 4 + 1], s2 = nh[tid * 4 + 2], s3 = nh[tid * 4 + 3];
    part[tid] = s0 + s1 + s2 + s3;
    __syncthreads();
    for (int st = 1; st < 256; st <<= 1) {
        int v = 0;
        if (tid >= st) v = part[tid - st];
        __syncthreads();
        if (tid >= st) part[tid] += v;
        __syncthreads();
    }
    int e0 = (tid ? part[tid - 1] : 0);
    int e1 = e0 + s0, e2 = e1 + s1, e3 = e2 + s2;
    cur[tid * 4 + 0] = e0; cur[tid * 4 + 1] = e1;
    cur[tid * 4 + 2] = e2; cur[tid * 4 + 3] = e3;
    int excl[4] = {e0, e1, e2, e3};
    int cval[4] = {s0, s1, s2, s3};
#pragma unroll
    for (int j = 0; j < 4; ++j) {
        int nl = tid * 4 + j;
        if (nl < limit) {
            cnt[nodeBase + nl] = cval[j];
            off[nodeBase + nl] = beg + excl[j];
        }
    }
    __syncthreads();
    for (int i = beg + tid; i < end; i += 256) {
        unsigned long long en = ebuf[i];
        int pos = atomicAdd(&cur[(int)(en >> 32) - nodeBase], 1);
        csr_e[beg + pos] = (int)(unsigned)en;
    }
}

// ---------------------------------------------------------------------------
// Gather: 8-lane group per node (natural order); lane = 8 features.
// 4x unroll: 4 csr loads + 4 h/comb row-pairs in flight per group.
// z[n] = relu((1+eps)*h[n] + sum_e relu(h[src] + comb[combo]))  (bf16 out)
// ---------------------------------------------------------------------------
__global__ __launch_bounds__(256) void gather_kernel(
    const int* __restrict__ cnt, const int* __restrict__ off,
    const int* __restrict__ csr_e, const unsigned short* __restrict__ h,
    const float* __restrict__ comb_l, const float* __restrict__ eps_p,
    unsigned short* __restrict__ zbuf)
{
    const int tid = threadIdx.x;
    const int lane = tid & 63;
    const int grp = lane >> 3;                    // group 0..7 in wave
    const int fo = (lane & 7) << 3;               // 8 features per lane
    const int n = blockIdx.x * 32 + (tid >> 6) * 8 + grp;   // N_NODES%32==0

    const int beg = off[n];
    const int end = beg + cnt[n];

    const f32x2 zero2 = {0.f, 0.f};
    f32x2 a0 = zero2, a1 = zero2, a2 = zero2, a3 = zero2;

#define EDGE_ACC(PK)                                                               \
    {                                                                              \
        int pk_ = (PK);                                                            \
        uint4 hv = *reinterpret_cast<const uint4*>(h + (pk_ & 0x1FFFF) * HID + fo);\
        const float4* ep_ = reinterpret_cast<const float4*>(comb_l + (pk_ >> 17) * HID + fo); \
        float4 e0_ = ep_[0], e1_ = ep_[1];                                         \
        a0 += __builtin_elementwise_max(bfpair(hv.x) + (f32x2){e0_.x, e0_.y}, zero2); \
        a1 += __builtin_elementwise_max(bfpair(hv.y) + (f32x2){e0_.z, e0_.w}, zero2); \
        a2 += __builtin_elementwise_max(bfpair(hv.z) + (f32x2){e1_.x, e1_.y}, zero2); \
        a3 += __builtin_elementwise_max(bfpair(hv.w) + (f32x2){e1_.z, e1_.w}, zero2); \
    }

    int i = beg;
    for (; i + 3 < end; i += 4) {
        int pk0 = csr_e[i];
        int pk1 = csr_e[i + 1];
        int pk2 = csr_e[i + 2];
        int pk3 = csr_e[i + 3];
        EDGE_ACC(pk0);
        EDGE_ACC(pk1);
        EDGE_ACC(pk2);
        EDGE_ACC(pk3);
    }
    for (; i < end; ++i) EDGE_ACC(csr_e[i]);
#undef EDGE_ACC

    uint4 hn = *reinterpret_cast<const uint4*>(h + (size_t)n * HID + fo);
    float ep1 = 1.0f + eps_p[0];
    f32x2 ep2 = {ep1, ep1};
    f32x2 z0 = __builtin_elementwise_max(ep2 * bfpair(hn.x) + a0, zero2);
    f32x2 z1 = __builtin_elementwise_max(ep2 * bfpair(hn.y) + a1, zero2);
    f32x2 z2 = __builtin_elementwise_max(ep2 * bfpair(hn.z) + a2, zero2);
    f32x2 z3 = __builtin_elementwise_max(ep2 * bfpair(hn.w) + a3, zero2);
    uint4 o;
    o.x = pack2bf(z0.x, z0.y);
    o.y = pack2bf(z1.x, z1.y);
    o.z = pack2bf(z2.x, z2.y);
    o.w = pack2bf(z3.x, z3.y);
    *reinterpret_cast<uint4*>(zbuf + (size_t)n * HID + fo) = o;
}

// ---------------------------------------------------------------------------
// MFMA node MLP, 128-node tiles.
// ---------------------------------------------------------------------------
__global__ __launch_bounds__(256) void mlp_kernel(
    const unsigned short* __restrict__ zbuf, unsigned short* __restrict__ h,
    const unsigned short* __restrict__ w1b, const unsigned short* __restrict__ w2b,
    const float* __restrict__ alpha, const float* __restrict__ beta,
    const float* __restrict__ b2, const int* __restrict__ batch,
    float* __restrict__ out, int out_col, int write_h)
{
    __shared__ unsigned short us[128 * MLP_HID];   // 32 KB
    __shared__ int sbatch[128];

    const int tid = threadIdx.x;
    const int lane = tid & 63;
    const int w = __builtin_amdgcn_readfirstlane(tid >> 6);
    const int base = blockIdx.x * 128;
    const int r16 = lane & 15;
    const int g4 = lane >> 4;                     // 0..3

    if (tid < 128) sbatch[tid] = (base + tid < N_NODES) ? batch[base + tid] : -1;

    bf16x8 awf[2][2];
#pragma unroll
    for (int mo = 0; mo < 2; ++mo)
#pragma unroll
        for (int kt = 0; kt < 2; ++kt) {
            int o = (2 * w + mo) * 16 + r16;
            awf[mo][kt] = *reinterpret_cast<const bf16x8*>(w1b + o * HID + kt * 32 + g4 * 8);
        }
    float4 al[2], be[2];
#pragma unroll
    for (int mo = 0; mo < 2; ++mo) {
        int o0 = (2 * w + mo) * 16 + g4 * 4;
        al[mo] = *reinterpret_cast<const float4*>(alpha + o0);
        be[mo] = *reinterpret_cast<const float4*>(beta + o0);
    }

    char* usb = (char*)us;
#pragma unroll
    for (int nt = 0; nt < 8; ++nt) {
        bf16x8 zf[2];
#pragma unroll
        for (int kt = 0; kt < 2; ++kt)
            zf[kt] = *reinterpret_cast<const bf16x8*>(
                zbuf + (size_t)(base + nt * 16 + r16) * HID + kt * 32 + g4 * 8);
        f32x4 acc[2] = {(f32x4){0.f, 0.f, 0.f, 0.f}, (f32x4){0.f, 0.f, 0.f, 0.f}};
#pragma unroll
        for (int mo = 0; mo < 2; ++mo)
#pragma unroll
            for (int kt = 0; kt < 2; ++kt)
                acc[mo] = __builtin_amdgcn_mfma_f32_16x16x32_bf16(
                    awf[mo][kt], zf[kt], acc[mo], 0, 0, 0);
        int node = nt * 16 + r16;
#pragma unroll
        for (int mo = 0; mo < 2; ++mo) {
            int o0 = (2 * w + mo) * 16 + g4 * 4;
            f32x4 a = acc[mo];
            unsigned lo = pack2bf(fmaxf(a[0] * al[mo].x + be[mo].x, 0.f),
                                  fmaxf(a[1] * al[mo].y + be[mo].y, 0.f));
            unsigned hi = pack2bf(fmaxf(a[2] * al[mo].z + be[mo].z, 0.f),
                                  fmaxf(a[3] * al[mo].w + be[mo].w, 0.f));
            int byte = (node * 256 + o0 * 2) ^ ((node & 7) << 4);
            *reinterpret_cast<uint2*>(usb + byte) = make_uint2(lo, hi);
        }
    }
    __syncthreads();

    bf16x8 b2frag[4];
#pragma unroll
    for (int kt = 0; kt < 4; ++kt)
        b2frag[kt] = *reinterpret_cast<const bf16x8*>(
            w2b + (w * 16 + r16) * MLP_HID + kt * 32 + g4 * 8);

    const int o = w * 16 + r16;
    const float bias = b2[o];
    int gprev = -2;
    float run = 0.f;
#pragma unroll
    for (int mt = 0; mt < 8; ++mt) {
        f32x4 acc2 = (f32x4){0.f, 0.f, 0.f, 0.f};
#pragma unroll
        for (int kt = 0; kt < 4; ++kt) {
            int node = mt * 16 + r16;
            int byte = (node * 256 + (kt * 32 + g4 * 8) * 2) ^ ((node & 7) << 4);
            bf16x8 af = *reinterpret_cast<const bf16x8*>(usb + byte);
            acc2 = __builtin_amdgcn_mfma_f32_16x16x32_bf16(af, b2frag[kt], acc2, 0, 0, 0);
        }
#pragma unroll
        for (int r = 0; r < 4; ++r) {
            int node = mt * 16 + g4 * 4 + r;
            int gn = base + node;
            float v = fmaxf(acc2[r] + bias, 0.f);
            if (write_h && gn < N_NODES) h[(size_t)gn * HID + o] = f2bf(v);
            int gb = sbatch[node];
            if (gb != gprev) {
                if (gprev >= 0) atomicAdd(&out[gprev * 256 + out_col + o], run);
                run = 0.f;
                gprev = gb;
            }
            if (gb >= 0) run += v;
        }
    }
    if (gprev >= 0) atomicAdd(&out[gprev * 256 + out_col + o], run);
}

// ---------------------------------------------------------------------------
extern "C" void kernel_launch(void* const* d_in, const int* in_sizes, int n_in,
                              void* d_out, int out_size, void* d_ws, size_t ws_size,
                              hipStream_t stream)
{
    const int*   x        = (const int*)d_in[0];
    const int*   ei       = (const int*)d_in[1];
    const int*   ea       = (const int*)d_in[2];
    const int*   batch    = (const int*)d_in[3];
    const float* atom_emb = (const float*)d_in[4];
    const float* edge_emb = (const float*)d_in[5];
    const float* w1       = (const float*)d_in[6];
    const float* b1       = (const float*)d_in[7];
    const float* bn_g     = (const float*)d_in[8];
    const float* bn_b     = (const float*)d_in[9];
    const float* bn_m     = (const float*)d_in[10];
    const float* bn_v     = (const float*)d_in[11];
    const float* w2       = (const float*)d_in[12];
    const float* b2       = (const float*)d_in[13];
    const float* eps      = (const float*)d_in[14];

    float* out = (float*)d_out;

    // workspace layout (all chunks 16B-aligned)
    const size_t NODE_PAD = 100096;
    char* ws = (char*)d_ws;
    unsigned short* h     = (unsigned short*)ws; ws += NODE_PAD * HID * 2;            // 12.8 MB
    unsigned short* zbuf  = (unsigned short*)ws; ws += NODE_PAD * HID * 2;            // 12.8 MB
    float* comb           = (float*)ws;          ws += (size_t)3 * N_COMBO * HID * 4; // 203 KB
    unsigned short* w1b   = (unsigned short*)ws; ws += (size_t)3 * MLP_HID * HID * 2;
    unsigned short* w2b   = (unsigned short*)ws; ws += (size_t)3 * HID * MLP_HID * 2;
    float* alpha          = (float*)ws;          ws += (size_t)3 * MLP_HID * 4;
    float* betab          = (float*)ws;          ws += (size_t)3 * MLP_HID * 4;
    int*   cnt            = (int*)ws;            ws += (size_t)N_NODES * 4;
    int*   off            = (int*)ws;            ws += (size_t)N_NODES * 4;
    int*   bcur           = (int*)ws;            ws += 128 * 4;
    unsigned long long* ebuf = (unsigned long long*)ws; ws += (size_t)NBUCK * BCAP * 8; // 16.1 MB
    int*   csr_e          = (int*)ws;            ws += (size_t)NBUCK * BCAP * 4;      // 8.0 MB

    const int nblk128 = (N_NODES + 127) / 128;   // 782

    hipMemsetAsync(out, 0, (size_t)N_GRAPHS * 256 * sizeof(float), stream);

    misc_kernel<<<NB_EMBED + NB_PREP + 1, 256, 0, stream>>>(
        x, atom_emb, batch, h, out,
        edge_emb, w1, w2, b1, bn_g, bn_b, bn_m, bn_v,
        comb, w1b, w2b, alpha, betab, bcur);

    bscatter_kernel<<<(N_EDGES + CHUNK - 1) / CHUNK, 256, 0, stream>>>(ei, ea, bcur, ebuf);
    csr_build_kernel<<<NBUCK, 256, 0, stream>>>(ebuf, bcur, cnt, off, csr_e);

    for (int l = 0; l < 3; ++l) {
        gather_kernel<<<N_NODES / 32, 256, 0, stream>>>(
            cnt, off, csr_e, h, comb + (size_t)l * N_COMBO * HID, eps + l, zbuf);
        mlp_kernel<<<nblk128, 256, 0, stream>>>(
            zbuf, h,
            w1b + (size_t)l * MLP_HID * HID, w2b + (size_t)l * HID * MLP_HID,
            alpha + (size_t)l * MLP_HID, betab + (size_t)l * MLP_HID,
            b2 + (size_t)l * HID, batch, out, (l + 1) * HID, (l < 2) ? 1 : 0);
    }
}

// Round 17
// 272.565 us; speedup vs baseline: 2.0189x; 1.0510x over previous
//
#include <hip/hip_runtime.h>

#define N_NODES 100000
#define N_EDGES 1600000
#define N_GRAPHS 1024
#define HID 64
#define MLP_HID 128
#define N_COMBO 264    // 22*6*2 edge-attr combinations
#define NBUCK 98       // ceil(N_NODES / 1024)
#define BCAP 20480     // fixed bucket capacity (mean 16384)
#define CHUNK 6144     // edges per bscatter block (48KB LDS staging)

#define NB_EMBED 1563  // (N_NODES+63)/64
#define NPREP (3*N_COMBO*HID + 3*MLP_HID*HID + 3*MLP_HID)   // 75648
#define NB_PREP 296    // ceil(NPREP/256)

typedef __attribute__((ext_vector_type(8))) short bf16x8;
typedef __attribute__((ext_vector_type(4))) float f32x4;
typedef __attribute__((ext_vector_type(2))) float f32x2;

static __device__ __forceinline__ float bf2f(unsigned short u) {
    union { unsigned int i; float f; } v; v.i = ((unsigned int)u) << 16; return v.f;
}
static __device__ __forceinline__ unsigned short f2bf(float f) {
    union { float f; unsigned int i; } v; v.f = f;
    unsigned int u = v.i;
    unsigned int r = u + 0x7FFFu + ((u >> 16) & 1u);   // RNE
    return (unsigned short)(r >> 16);
}
static __device__ __forceinline__ f32x2 bfpair(unsigned int u) {
    union { unsigned int i; float f; } lo, hi;
    lo.i = u << 16;
    hi.i = u & 0xFFFF0000u;
    f32x2 r; r.x = lo.f; r.y = hi.f; return r;
}
static __device__ __forceinline__ unsigned int pack2bf(float a, float b) {
    return (unsigned int)f2bf(a) | ((unsigned int)f2bf(b) << 16);
}

// ---------------------------------------------------------------------------
// Fused misc kernel: [0,NB_EMBED) atom-embed + pooled[0];
//                    [NB_EMBED, +NB_PREP) weight/comb prep;
//                    last block: zero bcur.
// ---------------------------------------------------------------------------
__global__ __launch_bounds__(256) void misc_kernel(
    const int* __restrict__ x, const float* __restrict__ atom_emb,
    const int* __restrict__ batch, unsigned short* __restrict__ h,
    float* __restrict__ out,
    const float* __restrict__ edge_emb,
    const float* __restrict__ w1, const float* __restrict__ w2,
    const float* __restrict__ b1, const float* __restrict__ bn_g,
    const float* __restrict__ bn_b, const float* __restrict__ bn_m,
    const float* __restrict__ bn_v,
    float* __restrict__ comb,
    unsigned short* __restrict__ w1b, unsigned short* __restrict__ w2b,
    float* __restrict__ alpha, float* __restrict__ beta,
    int* __restrict__ bcur)
{
    const int bid = blockIdx.x;
    const int tid = threadIdx.x;

    if (bid < NB_EMBED) {
        int f = tid & 63;
        int q = __builtin_amdgcn_readfirstlane(tid >> 6);   // wave-uniform
        int base = bid * 64 + q * 16;
        float run = 0.f;
        int cg = -1;
        for (int k = 0; k < 16; ++k) {
            int gn = base + k;
            if (gn >= N_NODES) break;
            const int* xp = x + gn * 9;                     // uniform -> s_load
            float acc = 0.f;
#pragma unroll
            for (int j = 0; j < 9; ++j) {
                int idx = xp[j];
                acc += atom_emb[(j * 119 + idx) * HID + f]; // coalesced 256B
            }
            h[(size_t)gn * HID + f] = f2bf(acc);
            int g = batch[gn];                              // uniform
            if (g != cg) {
                if (cg >= 0) atomicAdd(&out[cg * 256 + f], run);
                run = 0.f; cg = g;
            }
            run += acc;
        }
        if (cg >= 0) atomicAdd(&out[cg * 256 + f], run);
    } else if (bid < NB_EMBED + NB_PREP) {
        int t = (bid - NB_EMBED) * 256 + tid;
        const int NC = 3 * N_COMBO * HID;   // 50688
        const int NW = 3 * MLP_HID * HID;   // 24576
        if (t < NC) {
            int d = t & 63;
            int c = (t >> 6) % N_COMBO;
            int l = (t >> 6) / N_COMBO;
            int a0 = c / 12, r = c % 12, a1 = r >> 1, a2 = r & 1;
            const float* base = edge_emb + (size_t)l * 3 * 22 * HID;
            comb[t] = base[(0 * 22 + a0) * HID + d]
                    + base[(1 * 22 + a1) * HID + d]
                    + base[(2 * 22 + a2) * HID + d];
        } else if (t < NC + NW) {
            int i = t - NC;
            w1b[i] = f2bf(w1[i]);
            w2b[i] = f2bf(w2[i]);
        } else if (t < NC + NW + 3 * MLP_HID) {
            int i = t - NC - NW;
            float a = rsqrtf(bn_v[i] + 1e-5f) * bn_g[i];
            alpha[i] = a;
            beta[i] = (b1[i] - bn_m[i]) * a + bn_b[i];
        }
    } else {
        if (tid < 128) bcur[tid] = 0;
    }
}

// ---------------------------------------------------------------------------
// bscatter: LDS-staged reorder by bucket into fixed-capacity regions.
// edge record = (src | combo<<17) | dst<<32  (as u64)
// ---------------------------------------------------------------------------
__global__ __launch_bounds__(256) void bscatter_kernel(
    const int* __restrict__ ei, const int* __restrict__ ea,
    int* __restrict__ bcur, unsigned long long* __restrict__ ebuf)
{
    __shared__ unsigned long long stage[CHUNK];   // 48 KB
    __shared__ int hist[NBUCK];
    __shared__ int lbase[NBUCK];
    __shared__ int shift[NBUCK];
    __shared__ int sbuf[128];

    int tid = threadIdx.x;
    int base = blockIdx.x * CHUNK;
    int n_here = min(CHUNK, N_EDGES - base);

    for (int i = tid; i < NBUCK; i += 256) hist[i] = 0;
    __syncthreads();
    for (int i = tid; i < n_here; i += 256)
        atomicAdd(&hist[ei[N_EDGES + base + i] >> 10], 1);
    __syncthreads();
    if (tid < 128) sbuf[tid] = (tid < NBUCK) ? hist[tid] : 0;
    __syncthreads();
    for (int s = 1; s < 128; s <<= 1) {
        int u = 0;
        if (tid < 128 && tid >= s) u = sbuf[tid - s];
        __syncthreads();
        if (tid < 128) sbuf[tid] += u;
        __syncthreads();
    }
    if (tid < NBUCK) lbase[tid] = sbuf[tid] - hist[tid];
    __syncthreads();
    if (tid < NBUCK) {
        int c = hist[tid];
        if (c > 0) {
            int g = tid * BCAP + atomicAdd(&bcur[tid], c);
            shift[tid] = g - lbase[tid];
        }
        hist[tid] = lbase[tid];
    }
    __syncthreads();
    for (int i = tid; i < n_here; i += 256) {
        int e = base + i;
        int src = ei[e];
        int dst = ei[N_EDGES + e];
        int combo = (ea[e * 3 + 0] * 6 + ea[e * 3 + 1]) * 2 + ea[e * 3 + 2];
        int pos = atomicAdd(&hist[dst >> 10], 1);
        stage[pos] = (unsigned long long)(unsigned)(src | (combo << 17))
                   | ((unsigned long long)(unsigned)dst << 32);
    }
    __syncthreads();
    for (int i = tid; i < n_here; i += 256) {
        unsigned long long en = stage[i];
        ebuf[shift[(int)(en >> 32) >> 10] + i] = en;
    }
}

// ---------------------------------------------------------------------------
// csr_build: one block per bucket; exact per-node CSR within the bucket's
// region [b*BCAP, b*BCAP + bcur[b]); writes global cnt/off.
// ---------------------------------------------------------------------------
__global__ __launch_bounds__(256) void csr_build_kernel(
    const unsigned long long* __restrict__ ebuf, const int* __restrict__ bcur,
    int* __restrict__ cnt, int* __restrict__ off, int* __restrict__ csr_e)
{
    __shared__ int nh[1024];
    __shared__ int cur[1024];
    __shared__ int part[256];

    int b = blockIdx.x;
    int tid = threadIdx.x;
    int nodeBase = b << 10;
    int limit = min(1024, N_NODES - nodeBase);
    int beg = b * BCAP;
    int end = beg + bcur[b];

    for (int i = tid; i < 1024; i += 256) nh[i] = 0;
    __syncthreads();
    for (int i = beg + tid; i < end; i += 256)
        atomicAdd(&nh[(int)(ebuf[i] >> 32) - nodeBase], 1);
    __syncthreads();

    int s0 = nh[tid * 4], s1 = nh[tid * 4 + 1], s2 = nh[tid * 4 + 2], s3 = nh[tid * 4 + 3];
    part[tid] = s0 + s1 + s2 + s3;
    __syncthreads();
    for (int st = 1; st < 256; st <<= 1) {
        int v = 0;
        if (tid >= st) v = part[tid - st];
        __syncthreads();
        if (tid >= st) part[tid] += v;
        __syncthreads();
    }
    int e0 = (tid ? part[tid - 1] : 0);
    int e1 = e0 + s0, e2 = e1 + s1, e3 = e2 + s2;
    cur[tid * 4 + 0] = e0; cur[tid * 4 + 1] = e1;
    cur[tid * 4 + 2] = e2; cur[tid * 4 + 3] = e3;
    int excl[4] = {e0, e1, e2, e3};
    int cval[4] = {s0, s1, s2, s3};
#pragma unroll
    for (int j = 0; j < 4; ++j) {
        int nl = tid * 4 + j;
        if (nl < limit) {
            cnt[nodeBase + nl] = cval[j];
            off[nodeBase + nl] = beg + excl[j];
        }
    }
    __syncthreads();
    for (int i = beg + tid; i < end; i += 256) {
        unsigned long long en = ebuf[i];
        int pos = atomicAdd(&cur[(int)(en >> 32) - nodeBase], 1);
        csr_e[beg + pos] = (int)(unsigned)en;
    }
}

// ---------------------------------------------------------------------------
// Gather: 8-lane group per node (natural order); lane = 8 features.
// 2x loop with csr_e pair-prefetch (software pipeline depth 2).
// z[n] = relu((1+eps)*h[n] + sum_e relu(h[src] + comb[combo]))  (bf16 out)
// ---------------------------------------------------------------------------
__global__ __launch_bounds__(256) void gather_kernel(
    const int* __restrict__ cnt, const int* __restrict__ off,
    const int* __restrict__ csr_e, const unsigned short* __restrict__ h,
    const float* __restrict__ comb_l, const float* __restrict__ eps_p,
    unsigned short* __restrict__ zbuf)
{
    const int tid = threadIdx.x;
    const int lane = tid & 63;
    const int grp = lane >> 3;                    // group 0..7 in wave
    const int fo = (lane & 7) << 3;               // 8 features per lane
    const int n = blockIdx.x * 32 + (tid >> 6) * 8 + grp;   // N_NODES%32==0

    const int beg = off[n];
    const int end = beg + cnt[n];

    const f32x2 zero2 = {0.f, 0.f};
    f32x2 a0 = zero2, a1 = zero2, a2 = zero2, a3 = zero2;

#define EDGE_ACC(PK)                                                               \
    {                                                                              \
        int pk_ = (PK);                                                            \
        uint4 hv = *reinterpret_cast<const uint4*>(h + (pk_ & 0x1FFFF) * HID + fo);\
        const float4* ep_ = reinterpret_cast<const float4*>(comb_l + (pk_ >> 17) * HID + fo); \
        float4 e0_ = ep_[0], e1_ = ep_[1];                                         \
        a0 += __builtin_elementwise_max(bfpair(hv.x) + (f32x2){e0_.x, e0_.y}, zero2); \
        a1 += __builtin_elementwise_max(bfpair(hv.y) + (f32x2){e0_.z, e0_.w}, zero2); \
        a2 += __builtin_elementwise_max(bfpair(hv.z) + (f32x2){e1_.x, e1_.y}, zero2); \
        a3 += __builtin_elementwise_max(bfpair(hv.w) + (f32x2){e1_.z, e1_.w}, zero2); \
    }

    int i = beg;
    if (end - beg >= 2) {
        int pk0 = csr_e[i];
        int pk1 = csr_e[i + 1];
        for (; i + 3 < end; i += 2) {
            int nk0 = csr_e[i + 2];       // prefetch next pair
            int nk1 = csr_e[i + 3];
            EDGE_ACC(pk0);
            EDGE_ACC(pk1);
            pk0 = nk0;
            pk1 = nk1;
        }
        EDGE_ACC(pk0);
        EDGE_ACC(pk1);
        i += 2;
    }
    for (; i < end; ++i) EDGE_ACC(csr_e[i]);
#undef EDGE_ACC

    uint4 hn = *reinterpret_cast<const uint4*>(h + (size_t)n * HID + fo);
    float ep1 = 1.0f + eps_p[0];
    f32x2 ep2 = {ep1, ep1};
    f32x2 z0 = __builtin_elementwise_max(ep2 * bfpair(hn.x) + a0, zero2);
    f32x2 z1 = __builtin_elementwise_max(ep2 * bfpair(hn.y) + a1, zero2);
    f32x2 z2 = __builtin_elementwise_max(ep2 * bfpair(hn.z) + a2, zero2);
    f32x2 z3 = __builtin_elementwise_max(ep2 * bfpair(hn.w) + a3, zero2);
    uint4 o;
    o.x = pack2bf(z0.x, z0.y);
    o.y = pack2bf(z1.x, z1.y);
    o.z = pack2bf(z2.x, z2.y);
    o.w = pack2bf(z3.x, z3.y);
    *reinterpret_cast<uint4*>(zbuf + (size_t)n * HID + fo) = o;
}

// ---------------------------------------------------------------------------
// MFMA node MLP, 128-node tiles.
// ---------------------------------------------------------------------------
__global__ __launch_bounds__(256) void mlp_kernel(
    const unsigned short* __restrict__ zbuf, unsigned short* __restrict__ h,
    const unsigned short* __restrict__ w1b, const unsigned short* __restrict__ w2b,
    const float* __restrict__ alpha, const float* __restrict__ beta,
    const float* __restrict__ b2, const int* __restrict__ batch,
    float* __restrict__ out, int out_col, int write_h)
{
    __shared__ unsigned short us[128 * MLP_HID];   // 32 KB
    __shared__ int sbatch[128];

    const int tid = threadIdx.x;
    const int lane = tid & 63;
    const int w = __builtin_amdgcn_readfirstlane(tid >> 6);
    const int base = blockIdx.x * 128;
    const int r16 = lane & 15;
    const int g4 = lane >> 4;                     // 0..3

    if (tid < 128) sbatch[tid] = (base + tid < N_NODES) ? batch[base + tid] : -1;

    bf16x8 awf[2][2];
#pragma unroll
    for (int mo = 0; mo < 2; ++mo)
#pragma unroll
        for (int kt = 0; kt < 2; ++kt) {
            int o = (2 * w + mo) * 16 + r16;
            awf[mo][kt] = *reinterpret_cast<const bf16x8*>(w1b + o * HID + kt * 32 + g4 * 8);
        }
    float4 al[2], be[2];
#pragma unroll
    for (int mo = 0; mo < 2; ++mo) {
        int o0 = (2 * w + mo) * 16 + g4 * 4;
        al[mo] = *reinterpret_cast<const float4*>(alpha + o0);
        be[mo] = *reinterpret_cast<const float4*>(beta + o0);
    }

    char* usb = (char*)us;
#pragma unroll
    for (int nt = 0; nt < 8; ++nt) {
        bf16x8 zf[2];
#pragma unroll
        for (int kt = 0; kt < 2; ++kt)
            zf[kt] = *reinterpret_cast<const bf16x8*>(
                zbuf + (size_t)(base + nt * 16 + r16) * HID + kt * 32 + g4 * 8);
        f32x4 acc[2] = {(f32x4){0.f, 0.f, 0.f, 0.f}, (f32x4){0.f, 0.f, 0.f, 0.f}};
#pragma unroll
        for (int mo = 0; mo < 2; ++mo)
#pragma unroll
            for (int kt = 0; kt < 2; ++kt)
                acc[mo] = __builtin_amdgcn_mfma_f32_16x16x32_bf16(
                    awf[mo][kt], zf[kt], acc[mo], 0, 0, 0);
        int node = nt * 16 + r16;
#pragma unroll
        for (int mo = 0; mo < 2; ++mo) {
            int o0 = (2 * w + mo) * 16 + g4 * 4;
            f32x4 a = acc[mo];
            unsigned lo = pack2bf(fmaxf(a[0] * al[mo].x + be[mo].x, 0.f),
                                  fmaxf(a[1] * al[mo].y + be[mo].y, 0.f));
            unsigned hi = pack2bf(fmaxf(a[2] * al[mo].z + be[mo].z, 0.f),
                                  fmaxf(a[3] * al[mo].w + be[mo].w, 0.f));
            int byte = (node * 256 + o0 * 2) ^ ((node & 7) << 4);
            *reinterpret_cast<uint2*>(usb + byte) = make_uint2(lo, hi);
        }
    }
    __syncthreads();

    bf16x8 b2frag[4];
#pragma unroll
    for (int kt = 0; kt < 4; ++kt)
        b2frag[kt] = *reinterpret_cast<const bf16x8*>(
            w2b + (w * 16 + r16) * MLP_HID + kt * 32 + g4 * 8);

    const int o = w * 16 + r16;
    const float bias = b2[o];
    int gprev = -2;
    float run = 0.f;
#pragma unroll
    for (int mt = 0; mt < 8; ++mt) {
        f32x4 acc2 = (f32x4){0.f, 0.f, 0.f, 0.f};
#pragma unroll
        for (int kt = 0; kt < 4; ++kt) {
            int node = mt * 16 + r16;
            int byte = (node * 256 + (kt * 32 + g4 * 8) * 2) ^ ((node & 7) << 4);
            bf16x8 af = *reinterpret_cast<const bf16x8*>(usb + byte);
            acc2 = __builtin_amdgcn_mfma_f32_16x16x32_bf16(af, b2frag[kt], acc2, 0, 0, 0);
        }
#pragma unroll
        for (int r = 0; r < 4; ++r) {
            int node = mt * 16 + g4 * 4 + r;
            int gn = base + node;
            float v = fmaxf(acc2[r] + bias, 0.f);
            if (write_h && gn < N_NODES) h[(size_t)gn * HID + o] = f2bf(v);
            int gb = sbatch[node];
            if (gb != gprev) {
                if (gprev >= 0) atomicAdd(&out[gprev * 256 + out_col + o], run);
                run = 0.f;
                gprev = gb;
            }
            if (gb >= 0) run += v;
        }
    }
    if (gprev >= 0) atomicAdd(&out[gprev * 256 + out_col + o], run);
}

// ---------------------------------------------------------------------------
extern "C" void kernel_launch(void* const* d_in, const int* in_sizes, int n_in,
                              void* d_out, int out_size, void* d_ws, size_t ws_size,
                              hipStream_t stream)
{
    const int*   x        = (const int*)d_in[0];
    const int*   ei       = (const int*)d_in[1];
    const int*   ea       = (const int*)d_in[2];
    const int*   batch    = (const int*)d_in[3];
    const float* atom_emb = (const float*)d_in[4];
    const float* edge_emb = (const float*)d_in[5];
    const float* w1       = (const float*)d_in[6];
    const float* b1       = (const float*)d_in[7];
    const float* bn_g     = (const float*)d_in[8];
    const float* bn_b     = (const float*)d_in[9];
    const float* bn_m     = (const float*)d_in[10];
    const float* bn_v     = (const float*)d_in[11];
    const float* w2       = (const float*)d_in[12];
    const float* b2       = (const float*)d_in[13];
    const float* eps      = (const float*)d_in[14];

    float* out = (float*)d_out;

    // workspace layout (all chunks 16B-aligned)
    const size_t NODE_PAD = 100096;
    char* ws = (char*)d_ws;
    unsigned short* h     = (unsigned short*)ws; ws += NODE_PAD * HID * 2;            // 12.8 MB
    unsigned short* zbuf  = (unsigned short*)ws; ws += NODE_PAD * HID * 2;            // 12.8 MB
    float* comb           = (float*)ws;          ws += (size_t)3 * N_COMBO * HID * 4; // 203 KB
    unsigned short* w1b   = (unsigned short*)ws; ws += (size_t)3 * MLP_HID * HID * 2;
    unsigned short* w2b   = (unsigned short*)ws; ws += (size_t)3 * HID * MLP_HID * 2;
    float* alpha          = (float*)ws;          ws += (size_t)3 * MLP_HID * 4;
    float* betab          = (float*)ws;          ws += (size_t)3 * MLP_HID * 4;
    int*   cnt            = (int*)ws;            ws += (size_t)N_NODES * 4;
    int*   off            = (int*)ws;            ws += (size_t)N_NODES * 4;
    int*   bcur           = (int*)ws;            ws += 128 * 4;
    unsigned long long* ebuf = (unsigned long long*)ws; ws += (size_t)NBUCK * BCAP * 8; // 16.1 MB
    int*   csr_e          = (int*)ws;            ws += (size_t)NBUCK * BCAP * 4;      // 8.0 MB

    const int nblk128 = (N_NODES + 127) / 128;   // 782

    hipMemsetAsync(out, 0, (size_t)N_GRAPHS * 256 * sizeof(float), stream);

    misc_kernel<<<NB_EMBED + NB_PREP + 1, 256, 0, stream>>>(
        x, atom_emb, batch, h, out,
        edge_emb, w1, w2, b1, bn_g, bn_b, bn_m, bn_v,
        comb, w1b, w2b, alpha, betab, bcur);

    bscatter_kernel<<<(N_EDGES + CHUNK - 1) / CHUNK, 256, 0, stream>>>(ei, ea, bcur, ebuf);
    csr_build_kernel<<<NBUCK, 256, 0, stream>>>(ebuf, bcur, cnt, off, csr_e);

    for (int l = 0; l < 3; ++l) {
        gather_kernel<<<N_NODES / 32, 256, 0, stream>>>(
            cnt, off, csr_e, h, comb + (size_t)l * N_COMBO * HID, eps + l, zbuf);
        mlp_kernel<<<nblk128, 256, 0, stream>>>(
            zbuf, h,
            w1b + (size_t)l * MLP_HID * HID, w2b + (size_t)l * HID * MLP_HID,
            alpha + (size_t)l * MLP_HID, betab + (size_t)l * MLP_HID,
            b2 + (size_t)l * HID, batch, out, (l + 1) * HID, (l < 2) ? 1 : 0);
    }
}

// Round 18
// 272.340 us; speedup vs baseline: 2.0206x; 1.0008x over previous
//
#include <hip/hip_runtime.h>

#define N_NODES 100000
#define N_EDGES 1600000
#define N_GRAPHS 1024
#define HID 64
#define MLP_HID 128
#define N_COMBO 264    // 22*6*2 edge-attr combinations
#define NBUCK 98       // ceil(N_NODES / 1024)
#define BCAP 20480     // fixed bucket capacity (mean 16384)
#define CHUNK 6144     // edges per bscatter block (48KB LDS staging)

#define NB_EMBED 1563  // (N_NODES+63)/64
#define NPREP (3*N_COMBO*HID + 3*MLP_HID*HID + 3*MLP_HID)   // 75648
#define NB_PREP 296    // ceil(NPREP/256)

typedef __attribute__((ext_vector_type(8))) short bf16x8;
typedef __attribute__((ext_vector_type(4))) float f32x4;
typedef __attribute__((ext_vector_type(2))) float f32x2;

static __device__ __forceinline__ float bf2f(unsigned short u) {
    union { unsigned int i; float f; } v; v.i = ((unsigned int)u) << 16; return v.f;
}
static __device__ __forceinline__ unsigned short f2bf(float f) {
    union { float f; unsigned int i; } v; v.f = f;
    unsigned int u = v.i;
    unsigned int r = u + 0x7FFFu + ((u >> 16) & 1u);   // RNE
    return (unsigned short)(r >> 16);
}
static __device__ __forceinline__ f32x2 bfpair(unsigned int u) {
    union { unsigned int i; float f; } lo, hi;
    lo.i = u << 16;
    hi.i = u & 0xFFFF0000u;
    f32x2 r; r.x = lo.f; r.y = hi.f; return r;
}
static __device__ __forceinline__ unsigned int pack2bf(float a, float b) {
    return (unsigned int)f2bf(a) | ((unsigned int)f2bf(b) << 16);
}

// ---------------------------------------------------------------------------
// zero_kernel: blocks 0..255 zero out (1 float4/thread); block 256 zeros bcur.
// Replaces the 42us rocclr fillBuffer (tiny-grid, 25 GB/s) with ~4us.
// ---------------------------------------------------------------------------
__global__ __launch_bounds__(256) void zero_kernel(
    float* __restrict__ out, int* __restrict__ bcur)
{
    int bid = blockIdx.x;
    int tid = threadIdx.x;
    if (bid < 256) {
        int i = (bid * 256 + tid) * 4;           // 256*256*4 = 262144 floats
        *reinterpret_cast<float4*>(out + i) = make_float4(0.f, 0.f, 0.f, 0.f);
    } else {
        if (tid < 128) bcur[tid] = 0;
    }
}

// ---------------------------------------------------------------------------
// Fused misc kernel: [0,NB_EMBED) atom-embed + pooled[0];
//                    [NB_EMBED, +NB_PREP) weight/comb prep.
// ---------------------------------------------------------------------------
__global__ __launch_bounds__(256) void misc_kernel(
    const int* __restrict__ x, const float* __restrict__ atom_emb,
    const int* __restrict__ batch, unsigned short* __restrict__ h,
    float* __restrict__ out,
    const float* __restrict__ edge_emb,
    const float* __restrict__ w1, const float* __restrict__ w2,
    const float* __restrict__ b1, const float* __restrict__ bn_g,
    const float* __restrict__ bn_b, const float* __restrict__ bn_m,
    const float* __restrict__ bn_v,
    float* __restrict__ comb,
    unsigned short* __restrict__ w1b, unsigned short* __restrict__ w2b,
    float* __restrict__ alpha, float* __restrict__ beta)
{
    const int bid = blockIdx.x;
    const int tid = threadIdx.x;

    if (bid < NB_EMBED) {
        int f = tid & 63;
        int q = __builtin_amdgcn_readfirstlane(tid >> 6);   // wave-uniform
        int base = bid * 64 + q * 16;
        float run = 0.f;
        int cg = -1;
        for (int k = 0; k < 16; ++k) {
            int gn = base + k;
            if (gn >= N_NODES) break;
            const int* xp = x + gn * 9;                     // uniform -> s_load
            float acc = 0.f;
#pragma unroll
            for (int j = 0; j < 9; ++j) {
                int idx = xp[j];
                acc += atom_emb[(j * 119 + idx) * HID + f]; // coalesced 256B
            }
            h[(size_t)gn * HID + f] = f2bf(acc);
            int g = batch[gn];                              // uniform
            if (g != cg) {
                if (cg >= 0) atomicAdd(&out[cg * 256 + f], run);
                run = 0.f; cg = g;
            }
            run += acc;
        }
        if (cg >= 0) atomicAdd(&out[cg * 256 + f], run);
    } else {
        int t = (bid - NB_EMBED) * 256 + tid;
        const int NC = 3 * N_COMBO * HID;   // 50688
        const int NW = 3 * MLP_HID * HID;   // 24576
        if (t < NC) {
            int d = t & 63;
            int c = (t >> 6) % N_COMBO;
            int l = (t >> 6) / N_COMBO;
            int a0 = c / 12, r = c % 12, a1 = r >> 1, a2 = r & 1;
            const float* base = edge_emb + (size_t)l * 3 * 22 * HID;
            comb[t] = base[(0 * 22 + a0) * HID + d]
                    + base[(1 * 22 + a1) * HID + d]
                    + base[(2 * 22 + a2) * HID + d];
        } else if (t < NC + NW) {
            int i = t - NC;
            w1b[i] = f2bf(w1[i]);
            w2b[i] = f2bf(w2[i]);
        } else if (t < NC + NW + 3 * MLP_HID) {
            int i = t - NC - NW;
            float a = rsqrtf(bn_v[i] + 1e-5f) * bn_g[i];
            alpha[i] = a;
            beta[i] = (b1[i] - bn_m[i]) * a + bn_b[i];
        }
    }
}

// ---------------------------------------------------------------------------
// bscatter: LDS-staged reorder by bucket into fixed-capacity regions.
// edge record = (src | combo<<17) | dst<<32  (as u64)
// ---------------------------------------------------------------------------
__global__ __launch_bounds__(256) void bscatter_kernel(
    const int* __restrict__ ei, const int* __restrict__ ea,
    int* __restrict__ bcur, unsigned long long* __restrict__ ebuf)
{
    __shared__ unsigned long long stage[CHUNK];   // 48 KB
    __shared__ int hist[NBUCK];
    __shared__ int lbase[NBUCK];
    __shared__ int shift[NBUCK];
    __shared__ int sbuf[128];

    int tid = threadIdx.x;
    int base = blockIdx.x * CHUNK;
    int n_here = min(CHUNK, N_EDGES - base);

    for (int i = tid; i < NBUCK; i += 256) hist[i] = 0;
    __syncthreads();
    for (int i = tid; i < n_here; i += 256)
        atomicAdd(&hist[ei[N_EDGES + base + i] >> 10], 1);
    __syncthreads();
    if (tid < 128) sbuf[tid] = (tid < NBUCK) ? hist[tid] : 0;
    __syncthreads();
    for (int s = 1; s < 128; s <<= 1) {
        int u = 0;
        if (tid < 128 && tid >= s) u = sbuf[tid - s];
        __syncthreads();
        if (tid < 128) sbuf[tid] += u;
        __syncthreads();
    }
    if (tid < NBUCK) lbase[tid] = sbuf[tid] - hist[tid];
    __syncthreads();
    if (tid < NBUCK) {
        int c = hist[tid];
        if (c > 0) {
            int g = tid * BCAP + atomicAdd(&bcur[tid], c);
            shift[tid] = g - lbase[tid];
        }
        hist[tid] = lbase[tid];
    }
    __syncthreads();
    for (int i = tid; i < n_here; i += 256) {
        int e = base + i;
        int src = ei[e];
        int dst = ei[N_EDGES + e];
        int combo = (ea[e * 3 + 0] * 6 + ea[e * 3 + 1]) * 2 + ea[e * 3 + 2];
        int pos = atomicAdd(&hist[dst >> 10], 1);
        stage[pos] = (unsigned long long)(unsigned)(src | (combo << 17))
                   | ((unsigned long long)(unsigned)dst << 32);
    }
    __syncthreads();
    for (int i = tid; i < n_here; i += 256) {
        unsigned long long en = stage[i];
        ebuf[shift[(int)(en >> 32) >> 10] + i] = en;
    }
}

// ---------------------------------------------------------------------------
// csr_build: one block per bucket; exact per-node CSR within the bucket's
// region [b*BCAP, b*BCAP + bcur[b]); writes global cnt/off.
// ---------------------------------------------------------------------------
__global__ __launch_bounds__(256) void csr_build_kernel(
    const unsigned long long* __restrict__ ebuf, const int* __restrict__ bcur,
    int* __restrict__ cnt, int* __restrict__ off, int* __restrict__ csr_e)
{
    __shared__ int nh[1024];
    __shared__ int cur[1024];
    __shared__ int part[256];

    int b = blockIdx.x;
    int tid = threadIdx.x;
    int nodeBase = b << 10;
    int limit = min(1024, N_NODES - nodeBase);
    int beg = b * BCAP;
    int end = beg + bcur[b];

    for (int i = tid; i < 1024; i += 256) nh[i] = 0;
    __syncthreads();
    for (int i = beg + tid; i < end; i += 256)
        atomicAdd(&nh[(int)(ebuf[i] >> 32) - nodeBase], 1);
    __syncthreads();

    int s0 = nh[tid * 4], s1 = nh[tid * 4 + 1], s2 = nh[tid * 4 + 2], s3 = nh[tid * 4 + 3];
    part[tid] = s0 + s1 + s2 + s3;
    __syncthreads();
    for (int st = 1; st < 256; st <<= 1) {
        int v = 0;
        if (tid >= st) v = part[tid - st];
        __syncthreads();
        if (tid >= st) part[tid] += v;
        __syncthreads();
    }
    int e0 = (tid ? part[tid - 1] : 0);
    int e1 = e0 + s0, e2 = e1 + s1, e3 = e2 + s2;
    cur[tid * 4 + 0] = e0; cur[tid * 4 + 1] = e1;
    cur[tid * 4 + 2] = e2; cur[tid * 4 + 3] = e3;
    int excl[4] = {e0, e1, e2, e3};
    int cval[4] = {s0, s1, s2, s3};
#pragma unroll
    for (int j = 0; j < 4; ++j) {
        int nl = tid * 4 + j;
        if (nl < limit) {
            cnt[nodeBase + nl] = cval[j];
            off[nodeBase + nl] = beg + excl[j];
        }
    }
    __syncthreads();
    for (int i = beg + tid; i < end; i += 256) {
        unsigned long long en = ebuf[i];
        int pos = atomicAdd(&cur[(int)(en >> 32) - nodeBase], 1);
        csr_e[beg + pos] = (int)(unsigned)en;
    }
}

// ---------------------------------------------------------------------------
// Gather: 8-lane group per node (natural order); lane = 8 features.
// 2x loop with csr_e pair-prefetch (software pipeline depth 2).
// z[n] = relu((1+eps)*h[n] + sum_e relu(h[src] + comb[combo]))  (bf16 out)
// ---------------------------------------------------------------------------
__global__ __launch_bounds__(256) void gather_kernel(
    const int* __restrict__ cnt, const int* __restrict__ off,
    const int* __restrict__ csr_e, const unsigned short* __restrict__ h,
    const float* __restrict__ comb_l, const float* __restrict__ eps_p,
    unsigned short* __restrict__ zbuf)
{
    const int tid = threadIdx.x;
    const int lane = tid & 63;
    const int grp = lane >> 3;                    // group 0..7 in wave
    const int fo = (lane & 7) << 3;               // 8 features per lane
    const int n = blockIdx.x * 32 + (tid >> 6) * 8 + grp;   // N_NODES%32==0

    const int beg = off[n];
    const int end = beg + cnt[n];

    const f32x2 zero2 = {0.f, 0.f};
    f32x2 a0 = zero2, a1 = zero2, a2 = zero2, a3 = zero2;

#define EDGE_ACC(PK)                                                               \
    {                                                                              \
        int pk_ = (PK);                                                            \
        uint4 hv = *reinterpret_cast<const uint4*>(h + (pk_ & 0x1FFFF) * HID + fo);\
        const float4* ep_ = reinterpret_cast<const float4*>(comb_l + (pk_ >> 17) * HID + fo); \
        float4 e0_ = ep_[0], e1_ = ep_[1];                                         \
        a0 += __builtin_elementwise_max(bfpair(hv.x) + (f32x2){e0_.x, e0_.y}, zero2); \
        a1 += __builtin_elementwise_max(bfpair(hv.y) + (f32x2){e0_.z, e0_.w}, zero2); \
        a2 += __builtin_elementwise_max(bfpair(hv.z) + (f32x2){e1_.x, e1_.y}, zero2); \
        a3 += __builtin_elementwise_max(bfpair(hv.w) + (f32x2){e1_.z, e1_.w}, zero2); \
    }

    int i = beg;
    if (end - beg >= 2) {
        int pk0 = csr_e[i];
        int pk1 = csr_e[i + 1];
        for (; i + 3 < end; i += 2) {
            int nk0 = csr_e[i + 2];       // prefetch next pair
            int nk1 = csr_e[i + 3];
            EDGE_ACC(pk0);
            EDGE_ACC(pk1);
            pk0 = nk0;
            pk1 = nk1;
        }
        EDGE_ACC(pk0);
        EDGE_ACC(pk1);
        i += 2;
    }
    for (; i < end; ++i) EDGE_ACC(csr_e[i]);
#undef EDGE_ACC

    uint4 hn = *reinterpret_cast<const uint4*>(h + (size_t)n * HID + fo);
    float ep1 = 1.0f + eps_p[0];
    f32x2 ep2 = {ep1, ep1};
    f32x2 z0 = __builtin_elementwise_max(ep2 * bfpair(hn.x) + a0, zero2);
    f32x2 z1 = __builtin_elementwise_max(ep2 * bfpair(hn.y) + a1, zero2);
    f32x2 z2 = __builtin_elementwise_max(ep2 * bfpair(hn.z) + a2, zero2);
    f32x2 z3 = __builtin_elementwise_max(ep2 * bfpair(hn.w) + a3, zero2);
    uint4 o;
    o.x = pack2bf(z0.x, z0.y);
    o.y = pack2bf(z1.x, z1.y);
    o.z = pack2bf(z2.x, z2.y);
    o.w = pack2bf(z3.x, z3.y);
    *reinterpret_cast<uint4*>(zbuf + (size_t)n * HID + fo) = o;
}

// ---------------------------------------------------------------------------
// MFMA node MLP, 128-node tiles.
// ---------------------------------------------------------------------------
__global__ __launch_bounds__(256) void mlp_kernel(
    const unsigned short* __restrict__ zbuf, unsigned short* __restrict__ h,
    const unsigned short* __restrict__ w1b, const unsigned short* __restrict__ w2b,
    const float* __restrict__ alpha, const float* __restrict__ beta,
    const float* __restrict__ b2, const int* __restrict__ batch,
    float* __restrict__ out, int out_col, int write_h)
{
    __shared__ unsigned short us[128 * MLP_HID];   // 32 KB
    __shared__ int sbatch[128];

    const int tid = threadIdx.x;
    const int lane = tid & 63;
    const int w = __builtin_amdgcn_readfirstlane(tid >> 6);
    const int base = blockIdx.x * 128;
    const int r16 = lane & 15;
    const int g4 = lane >> 4;                     // 0..3

    if (tid < 128) sbatch[tid] = (base + tid < N_NODES) ? batch[base + tid] : -1;

    bf16x8 awf[2][2];
#pragma unroll
    for (int mo = 0; mo < 2; ++mo)
#pragma unroll
        for (int kt = 0; kt < 2; ++kt) {
            int o = (2 * w + mo) * 16 + r16;
            awf[mo][kt] = *reinterpret_cast<const bf16x8*>(w1b + o * HID + kt * 32 + g4 * 8);
        }
    float4 al[2], be[2];
#pragma unroll
    for (int mo = 0; mo < 2; ++mo) {
        int o0 = (2 * w + mo) * 16 + g4 * 4;
        al[mo] = *reinterpret_cast<const float4*>(alpha + o0);
        be[mo] = *reinterpret_cast<const float4*>(beta + o0);
    }

    char* usb = (char*)us;
#pragma unroll
    for (int nt = 0; nt < 8; ++nt) {
        bf16x8 zf[2];
#pragma unroll
        for (int kt = 0; kt < 2; ++kt)
            zf[kt] = *reinterpret_cast<const bf16x8*>(
                zbuf + (size_t)(base + nt * 16 + r16) * HID + kt * 32 + g4 * 8);
        f32x4 acc[2] = {(f32x4){0.f, 0.f, 0.f, 0.f}, (f32x4){0.f, 0.f, 0.f, 0.f}};
#pragma unroll
        for (int mo = 0; mo < 2; ++mo)
#pragma unroll
            for (int kt = 0; kt < 2; ++kt)
                acc[mo] = __builtin_amdgcn_mfma_f32_16x16x32_bf16(
                    awf[mo][kt], zf[kt], acc[mo], 0, 0, 0);
        int node = nt * 16 + r16;
#pragma unroll
        for (int mo = 0; mo < 2; ++mo) {
            int o0 = (2 * w + mo) * 16 + g4 * 4;
            f32x4 a = acc[mo];
            unsigned lo = pack2bf(fmaxf(a[0] * al[mo].x + be[mo].x, 0.f),
                                  fmaxf(a[1] * al[mo].y + be[mo].y, 0.f));
            unsigned hi = pack2bf(fmaxf(a[2] * al[mo].z + be[mo].z, 0.f),
                                  fmaxf(a[3] * al[mo].w + be[mo].w, 0.f));
            int byte = (node * 256 + o0 * 2) ^ ((node & 7) << 4);
            *reinterpret_cast<uint2*>(usb + byte) = make_uint2(lo, hi);
        }
    }
    __syncthreads();

    bf16x8 b2frag[4];
#pragma unroll
    for (int kt = 0; kt < 4; ++kt)
        b2frag[kt] = *reinterpret_cast<const bf16x8*>(
            w2b + (w * 16 + r16) * MLP_HID + kt * 32 + g4 * 8);

    const int o = w * 16 + r16;
    const float bias = b2[o];
    int gprev = -2;
    float run = 0.f;
#pragma unroll
    for (int mt = 0; mt < 8; ++mt) {
        f32x4 acc2 = (f32x4){0.f, 0.f, 0.f, 0.f};
#pragma unroll
        for (int kt = 0; kt < 4; ++kt) {
            int node = mt * 16 + r16;
            int byte = (node * 256 + (kt * 32 + g4 * 8) * 2) ^ ((node & 7) << 4);
            bf16x8 af = *reinterpret_cast<const bf16x8*>(usb + byte);
            acc2 = __builtin_amdgcn_mfma_f32_16x16x32_bf16(af, b2frag[kt], acc2, 0, 0, 0);
        }
#pragma unroll
        for (int r = 0; r < 4; ++r) {
            int node = mt * 16 + g4 * 4 + r;
            int gn = base + node;
            float v = fmaxf(acc2[r] + bias, 0.f);
            if (write_h && gn < N_NODES) h[(size_t)gn * HID + o] = f2bf(v);
            int gb = sbatch[node];
            if (gb != gprev) {
                if (gprev >= 0) atomicAdd(&out[gprev * 256 + out_col + o], run);
                run = 0.f;
                gprev = gb;
            }
            if (gb >= 0) run += v;
        }
    }
    if (gprev >= 0) atomicAdd(&out[gprev * 256 + out_col + o], run);
}

// ---------------------------------------------------------------------------
extern "C" void kernel_launch(void* const* d_in, const int* in_sizes, int n_in,
                              void* d_out, int out_size, void* d_ws, size_t ws_size,
                              hipStream_t stream)
{
    const int*   x        = (const int*)d_in[0];
    const int*   ei       = (const int*)d_in[1];
    const int*   ea       = (const int*)d_in[2];
    const int*   batch    = (const int*)d_in[3];
    const float* atom_emb = (const float*)d_in[4];
    const float* edge_emb = (const float*)d_in[5];
    const float* w1       = (const float*)d_in[6];
    const float* b1       = (const float*)d_in[7];
    const float* bn_g     = (const float*)d_in[8];
    const float* bn_b     = (const float*)d_in[9];
    const float* bn_m     = (const float*)d_in[10];
    const float* bn_v     = (const float*)d_in[11];
    const float* w2       = (const float*)d_in[12];
    const float* b2       = (const float*)d_in[13];
    const float* eps      = (const float*)d_in[14];

    float* out = (float*)d_out;

    // workspace layout (all chunks 16B-aligned)
    const size_t NODE_PAD = 100096;
    char* ws = (char*)d_ws;
    unsigned short* h     = (unsigned short*)ws; ws += NODE_PAD * HID * 2;            // 12.8 MB
    unsigned short* zbuf  = (unsigned short*)ws; ws += NODE_PAD * HID * 2;            // 12.8 MB
    float* comb           = (float*)ws;          ws += (size_t)3 * N_COMBO * HID * 4; // 203 KB
    unsigned short* w1b   = (unsigned short*)ws; ws += (size_t)3 * MLP_HID * HID * 2;
    unsigned short* w2b   = (unsigned short*)ws; ws += (size_t)3 * HID * MLP_HID * 2;
    float* alpha          = (float*)ws;          ws += (size_t)3 * MLP_HID * 4;
    float* betab          = (float*)ws;          ws += (size_t)3 * MLP_HID * 4;
    int*   cnt            = (int*)ws;            ws += (size_t)N_NODES * 4;
    int*   off            = (int*)ws;            ws += (size_t)N_NODES * 4;
    int*   bcur           = (int*)ws;            ws += 128 * 4;
    unsigned long long* ebuf = (unsigned long long*)ws; ws += (size_t)NBUCK * BCAP * 8; // 16.1 MB
    int*   csr_e          = (int*)ws;            ws += (size_t)NBUCK * BCAP * 4;      // 8.0 MB

    const int nblk128 = (N_NODES + 127) / 128;   // 782

    zero_kernel<<<257, 256, 0, stream>>>(out, bcur);

    misc_kernel<<<NB_EMBED + NB_PREP, 256, 0, stream>>>(
        x, atom_emb, batch, h, out,
        edge_emb, w1, w2, b1, bn_g, bn_b, bn_m, bn_v,
        comb, w1b, w2b, alpha, betab);

    bscatter_kernel<<<(N_EDGES + CHUNK - 1) / CHUNK, 256, 0, stream>>>(ei, ea, bcur, ebuf);
    csr_build_kernel<<<NBUCK, 256, 0, stream>>>(ebuf, bcur, cnt, off, csr_e);

    for (int l = 0; l < 3; ++l) {
        gather_kernel<<<N_NODES / 32, 256, 0, stream>>>(
            cnt, off, csr_e, h, comb + (size_t)l * N_COMBO * HID, eps + l, zbuf);
        mlp_kernel<<<nblk128, 256, 0, stream>>>(
            zbuf, h,
            w1b + (size_t)l * MLP_HID * HID, w2b + (size_t)l * HID * MLP_HID,
            alpha + (size_t)l * MLP_HID, betab + (size_t)l * MLP_HID,
            b2 + (size_t)l * HID, batch, out, (l + 1) * HID, (l < 2) ? 1 : 0);
    }
}

// Round 19
// 262.531 us; speedup vs baseline: 2.0961x; 1.0374x over previous
//
#include <hip/hip_runtime.h>

#define N_NODES 100000
#define N_EDGES 1600000
#define N_GRAPHS 1024
#define HID 64
#define MLP_HID 128
#define N_COMBO 264    // 22*6*2 edge-attr combinations
#define NBUCK 98       // ceil(N_NODES / 1024)
#define BCAP 20480     // fixed bucket capacity (mean 16384)
#define CHUNK 4096     // edges per bscatter block (32KB LDS staging)

#define NB_EMBED 1563  // (N_NODES+63)/64
#define NPREP (3*N_COMBO*HID + 3*MLP_HID*HID + 3*MLP_HID)   // 75648
#define NB_PREP 296    // ceil(NPREP/256)
#define NB_SCAT 391    // ceil(N_EDGES/CHUNK)

typedef __attribute__((ext_vector_type(8))) short bf16x8;
typedef __attribute__((ext_vector_type(4))) float f32x4;
typedef __attribute__((ext_vector_type(2))) float f32x2;

static __device__ __forceinline__ float bf2f(unsigned short u) {
    union { unsigned int i; float f; } v; v.i = ((unsigned int)u) << 16; return v.f;
}
static __device__ __forceinline__ unsigned short f2bf(float f) {
    union { float f; unsigned int i; } v; v.f = f;
    unsigned int u = v.i;
    unsigned int r = u + 0x7FFFu + ((u >> 16) & 1u);   // RNE
    return (unsigned short)(r >> 16);
}
static __device__ __forceinline__ f32x2 bfpair(unsigned int u) {
    union { unsigned int i; float f; } lo, hi;
    lo.i = u << 16;
    hi.i = u & 0xFFFF0000u;
    f32x2 r; r.x = lo.f; r.y = hi.f; return r;
}
static __device__ __forceinline__ unsigned int pack2bf(float a, float b) {
    return (unsigned int)f2bf(a) | ((unsigned int)f2bf(b) << 16);
}

// ---------------------------------------------------------------------------
// zero_kernel: blocks 0..255 zero out (1 float4/thread); block 256 zeros bcur.
// ---------------------------------------------------------------------------
__global__ __launch_bounds__(256) void zero_kernel(
    float* __restrict__ out, int* __restrict__ bcur)
{
    int bid = blockIdx.x;
    int tid = threadIdx.x;
    if (bid < 256) {
        int i = (bid * 256 + tid) * 4;           // 256*256*4 = 262144 floats
        *reinterpret_cast<float4*>(out + i) = make_float4(0.f, 0.f, 0.f, 0.f);
    } else {
        if (tid < 128) bcur[tid] = 0;
    }
}

// ---------------------------------------------------------------------------
// Fused misc kernel: [0,NB_EMBED) atom-embed + pooled[0];
//                    [NB_EMBED, +NB_PREP) weight/comb prep;
//                    [+, +NB_SCAT) bucket-scatter chunks (independent work
//                    co-scheduled instead of a serial kernel).
// edge record = (src | combo<<17) | dst<<32  (as u64)
// ---------------------------------------------------------------------------
__global__ __launch_bounds__(256) void misc_kernel(
    const int* __restrict__ x, const float* __restrict__ atom_emb,
    const int* __restrict__ batch, unsigned short* __restrict__ h,
    float* __restrict__ out,
    const float* __restrict__ edge_emb,
    const float* __restrict__ w1, const float* __restrict__ w2,
    const float* __restrict__ b1, const float* __restrict__ bn_g,
    const float* __restrict__ bn_b, const float* __restrict__ bn_m,
    const float* __restrict__ bn_v,
    float* __restrict__ comb,
    unsigned short* __restrict__ w1b, unsigned short* __restrict__ w2b,
    float* __restrict__ alpha, float* __restrict__ beta,
    const int* __restrict__ ei, const int* __restrict__ ea,
    int* __restrict__ bcur, unsigned long long* __restrict__ ebuf)
{
    __shared__ unsigned long long stage[CHUNK];   // 32 KB (bscatter blocks only)
    __shared__ int hist[NBUCK];
    __shared__ int lbase[NBUCK];
    __shared__ int shift[NBUCK];
    __shared__ int sbuf[128];

    const int bid = blockIdx.x;
    const int tid = threadIdx.x;

    if (bid < NB_EMBED) {
        // ---- atom embedding (9-table sum) + pooled[0]
        int f = tid & 63;
        int q = __builtin_amdgcn_readfirstlane(tid >> 6);   // wave-uniform
        int base = bid * 64 + q * 16;
        float run = 0.f;
        int cg = -1;
        for (int k = 0; k < 16; ++k) {
            int gn = base + k;
            if (gn >= N_NODES) break;
            const int* xp = x + gn * 9;                     // uniform -> s_load
            float acc = 0.f;
#pragma unroll
            for (int j = 0; j < 9; ++j) {
                int idx = xp[j];
                acc += atom_emb[(j * 119 + idx) * HID + f]; // coalesced 256B
            }
            h[(size_t)gn * HID + f] = f2bf(acc);
            int g = batch[gn];                              // uniform
            if (g != cg) {
                if (cg >= 0) atomicAdd(&out[cg * 256 + f], run);
                run = 0.f; cg = g;
            }
            run += acc;
        }
        if (cg >= 0) atomicAdd(&out[cg * 256 + f], run);
    } else if (bid < NB_EMBED + NB_PREP) {
        // ---- prep: f32 comb table, bf16 weights, folded BN affine
        int t = (bid - NB_EMBED) * 256 + tid;
        const int NC = 3 * N_COMBO * HID;   // 50688
        const int NW = 3 * MLP_HID * HID;   // 24576
        if (t < NC) {
            int d = t & 63;
            int c = (t >> 6) % N_COMBO;
            int l = (t >> 6) / N_COMBO;
            int a0 = c / 12, r = c % 12, a1 = r >> 1, a2 = r & 1;
            const float* base = edge_emb + (size_t)l * 3 * 22 * HID;
            comb[t] = base[(0 * 22 + a0) * HID + d]
                    + base[(1 * 22 + a1) * HID + d]
                    + base[(2 * 22 + a2) * HID + d];
        } else if (t < NC + NW) {
            int i = t - NC;
            w1b[i] = f2bf(w1[i]);
            w2b[i] = f2bf(w2[i]);
        } else if (t < NC + NW + 3 * MLP_HID) {
            int i = t - NC - NW;
            float a = rsqrtf(bn_v[i] + 1e-5f) * bn_g[i];
            alpha[i] = a;
            beta[i] = (b1[i] - bn_m[i]) * a + bn_b[i];
        }
    } else {
        // ---- bscatter chunk: LDS-staged reorder by bucket, coalesced copy-out
        int base = (bid - NB_EMBED - NB_PREP) * CHUNK;
        int n_here = min(CHUNK, N_EDGES - base);

        for (int i = tid; i < NBUCK; i += 256) hist[i] = 0;
        __syncthreads();
        for (int i = tid; i < n_here; i += 256)
            atomicAdd(&hist[ei[N_EDGES + base + i] >> 10], 1);
        __syncthreads();
        if (tid < 128) sbuf[tid] = (tid < NBUCK) ? hist[tid] : 0;
        __syncthreads();
        for (int s = 1; s < 128; s <<= 1) {
            int u = 0;
            if (tid < 128 && tid >= s) u = sbuf[tid - s];
            __syncthreads();
            if (tid < 128) sbuf[tid] += u;
            __syncthreads();
        }
        if (tid < NBUCK) lbase[tid] = sbuf[tid] - hist[tid];
        __syncthreads();
        if (tid < NBUCK) {
            int c = hist[tid];
            if (c > 0) {
                int g = tid * BCAP + atomicAdd(&bcur[tid], c);
                shift[tid] = g - lbase[tid];
            }
            hist[tid] = lbase[tid];
        }
        __syncthreads();
        for (int i = tid; i < n_here; i += 256) {
            int e = base + i;
            int src = ei[e];
            int dst = ei[N_EDGES + e];
            int combo = (ea[e * 3 + 0] * 6 + ea[e * 3 + 1]) * 2 + ea[e * 3 + 2];
            int pos = atomicAdd(&hist[dst >> 10], 1);
            stage[pos] = (unsigned long long)(unsigned)(src | (combo << 17))
                       | ((unsigned long long)(unsigned)dst << 32);
        }
        __syncthreads();
        for (int i = tid; i < n_here; i += 256) {
            unsigned long long en = stage[i];
            ebuf[shift[(int)(en >> 32) >> 10] + i] = en;
        }
    }
}

// ---------------------------------------------------------------------------
// csr_build: one block per bucket; exact per-node CSR within the bucket's
// region [b*BCAP, b*BCAP + bcur[b]); writes global cnt/off.
// ---------------------------------------------------------------------------
__global__ __launch_bounds__(256) void csr_build_kernel(
    const unsigned long long* __restrict__ ebuf, const int* __restrict__ bcur,
    int* __restrict__ cnt, int* __restrict__ off, int* __restrict__ csr_e)
{
    __shared__ int nh[1024];
    __shared__ int cur[1024];
    __shared__ int part[256];

    int b = blockIdx.x;
    int tid = threadIdx.x;
    int nodeBase = b << 10;
    int limit = min(1024, N_NODES - nodeBase);
    int beg = b * BCAP;
    int end = beg + bcur[b];

    for (int i = tid; i < 1024; i += 256) nh[i] = 0;
    __syncthreads();
    for (int i = beg + tid; i < end; i += 256)
        atomicAdd(&nh[(int)(ebuf[i] >> 32) - nodeBase], 1);
    __syncthreads();

    int s0 = nh[tid * 4], s1 = nh[tid * 4 + 1], s2 = nh[tid * 4 + 2], s3 = nh[tid * 4 + 3];
    part[tid] = s0 + s1 + s2 + s3;
    __syncthreads();
    for (int st = 1; st < 256; st <<= 1) {
        int v = 0;
        if (tid >= st) v = part[tid - st];
        __syncthreads();
        if (tid >= st) part[tid] += v;
        __syncthreads();
    }
    int e0 = (tid ? part[tid - 1] : 0);
    int e1 = e0 + s0, e2 = e1 + s1, e3 = e2 + s2;
    cur[tid * 4 + 0] = e0; cur[tid * 4 + 1] = e1;
    cur[tid * 4 + 2] = e2; cur[tid * 4 + 3] = e3;
    int excl[4] = {e0, e1, e2, e3};
    int cval[4] = {s0, s1, s2, s3};
#pragma unroll
    for (int j = 0; j < 4; ++j) {
        int nl = tid * 4 + j;
        if (nl < limit) {
            cnt[nodeBase + nl] = cval[j];
            off[nodeBase + nl] = beg + excl[j];
        }
    }
    __syncthreads();
    for (int i = beg + tid; i < end; i += 256) {
        unsigned long long en = ebuf[i];
        int pos = atomicAdd(&cur[(int)(en >> 32) - nodeBase], 1);
        csr_e[beg + pos] = (int)(unsigned)en;
    }
}

// ---------------------------------------------------------------------------
// Gather: 8-lane group per node (natural order); lane = 8 features.
// 2x loop with csr_e pair-prefetch. launch_bounds(256,8): full occupancy hint.
// z[n] = relu((1+eps)*h[n] + sum_e relu(h[src] + comb[combo]))  (bf16 out)
// ---------------------------------------------------------------------------
__global__ __launch_bounds__(256, 8) void gather_kernel(
    const int* __restrict__ cnt, const int* __restrict__ off,
    const int* __restrict__ csr_e, const unsigned short* __restrict__ h,
    const float* __restrict__ comb_l, const float* __restrict__ eps_p,
    unsigned short* __restrict__ zbuf)
{
    const int tid = threadIdx.x;
    const int lane = tid & 63;
    const int grp = lane >> 3;                    // group 0..7 in wave
    const int fo = (lane & 7) << 3;               // 8 features per lane
    const int n = blockIdx.x * 32 + (tid >> 6) * 8 + grp;   // N_NODES%32==0

    const int beg = off[n];
    const int end = beg + cnt[n];

    const f32x2 zero2 = {0.f, 0.f};
    f32x2 a0 = zero2, a1 = zero2, a2 = zero2, a3 = zero2;

#define EDGE_ACC(PK)                                                               \
    {                                                                              \
        int pk_ = (PK);                                                            \
        uint4 hv = *reinterpret_cast<const uint4*>(h + (pk_ & 0x1FFFF) * HID + fo);\
        const float4* ep_ = reinterpret_cast<const float4*>(comb_l + (pk_ >> 17) * HID + fo); \
        float4 e0_ = ep_[0], e1_ = ep_[1];                                         \
        a0 += __builtin_elementwise_max(bfpair(hv.x) + (f32x2){e0_.x, e0_.y}, zero2); \
        a1 += __builtin_elementwise_max(bfpair(hv.y) + (f32x2){e0_.z, e0_.w}, zero2); \
        a2 += __builtin_elementwise_max(bfpair(hv.z) + (f32x2){e1_.x, e1_.y}, zero2); \
        a3 += __builtin_elementwise_max(bfpair(hv.w) + (f32x2){e1_.z, e1_.w}, zero2); \
    }

    int i = beg;
    if (end - beg >= 2) {
        int pk0 = csr_e[i];
        int pk1 = csr_e[i + 1];
        for (; i + 3 < end; i += 2) {
            int nk0 = csr_e[i + 2];       // prefetch next pair
            int nk1 = csr_e[i + 3];
            EDGE_ACC(pk0);
            EDGE_ACC(pk1);
            pk0 = nk0;
            pk1 = nk1;
        }
        EDGE_ACC(pk0);
        EDGE_ACC(pk1);
        i += 2;
    }
    for (; i < end; ++i) EDGE_ACC(csr_e[i]);
#undef EDGE_ACC

    uint4 hn = *reinterpret_cast<const uint4*>(h + (size_t)n * HID + fo);
    float ep1 = 1.0f + eps_p[0];
    f32x2 ep2 = {ep1, ep1};
    f32x2 z0 = __builtin_elementwise_max(ep2 * bfpair(hn.x) + a0, zero2);
    f32x2 z1 = __builtin_elementwise_max(ep2 * bfpair(hn.y) + a1, zero2);
    f32x2 z2 = __builtin_elementwise_max(ep2 * bfpair(hn.z) + a2, zero2);
    f32x2 z3 = __builtin_elementwise_max(ep2 * bfpair(hn.w) + a3, zero2);
    uint4 o;
    o.x = pack2bf(z0.x, z0.y);
    o.y = pack2bf(z1.x, z1.y);
    o.z = pack2bf(z2.x, z2.y);
    o.w = pack2bf(z3.x, z3.y);
    *reinterpret_cast<uint4*>(zbuf + (size_t)n * HID + fo) = o;
}

// ---------------------------------------------------------------------------
// MFMA node MLP, 128-node tiles.
// ---------------------------------------------------------------------------
__global__ __launch_bounds__(256) void mlp_kernel(
    const unsigned short* __restrict__ zbuf, unsigned short* __restrict__ h,
    const unsigned short* __restrict__ w1b, const unsigned short* __restrict__ w2b,
    const float* __restrict__ alpha, const float* __restrict__ beta,
    const float* __restrict__ b2, const int* __restrict__ batch,
    float* __restrict__ out, int out_col, int write_h)
{
    __shared__ unsigned short us[128 * MLP_HID];   // 32 KB
    __shared__ int sbatch[128];

    const int tid = threadIdx.x;
    const int lane = tid & 63;
    const int w = __builtin_amdgcn_readfirstlane(tid >> 6);
    const int base = blockIdx.x * 128;
    const int r16 = lane & 15;
    const int g4 = lane >> 4;                     // 0..3

    if (tid < 128) sbatch[tid] = (base + tid < N_NODES) ? batch[base + tid] : -1;

    bf16x8 awf[2][2];
#pragma unroll
    for (int mo = 0; mo < 2; ++mo)
#pragma unroll
        for (int kt = 0; kt < 2; ++kt) {
            int o = (2 * w + mo) * 16 + r16;
            awf[mo][kt] = *reinterpret_cast<const bf16x8*>(w1b + o * HID + kt * 32 + g4 * 8);
        }
    float4 al[2], be[2];
#pragma unroll
    for (int mo = 0; mo < 2; ++mo) {
        int o0 = (2 * w + mo) * 16 + g4 * 4;
        al[mo] = *reinterpret_cast<const float4*>(alpha + o0);
        be[mo] = *reinterpret_cast<const float4*>(beta + o0);
    }

    char* usb = (char*)us;
#pragma unroll
    for (int nt = 0; nt < 8; ++nt) {
        bf16x8 zf[2];
#pragma unroll
        for (int kt = 0; kt < 2; ++kt)
            zf[kt] = *reinterpret_cast<const bf16x8*>(
                zbuf + (size_t)(base + nt * 16 + r16) * HID + kt * 32 + g4 * 8);
        f32x4 acc[2] = {(f32x4){0.f, 0.f, 0.f, 0.f}, (f32x4){0.f, 0.f, 0.f, 0.f}};
#pragma unroll
        for (int mo = 0; mo < 2; ++mo)
#pragma unroll
            for (int kt = 0; kt < 2; ++kt)
                acc[mo] = __builtin_amdgcn_mfma_f32_16x16x32_bf16(
                    awf[mo][kt], zf[kt], acc[mo], 0, 0, 0);
        int node = nt * 16 + r16;
#pragma unroll
        for (int mo = 0; mo < 2; ++mo) {
            int o0 = (2 * w + mo) * 16 + g4 * 4;
            f32x4 a = acc[mo];
            unsigned lo = pack2bf(fmaxf(a[0] * al[mo].x + be[mo].x, 0.f),
                                  fmaxf(a[1] * al[mo].y + be[mo].y, 0.f));
            unsigned hi = pack2bf(fmaxf(a[2] * al[mo].z + be[mo].z, 0.f),
                                  fmaxf(a[3] * al[mo].w + be[mo].w, 0.f));
            int byte = (node * 256 + o0 * 2) ^ ((node & 7) << 4);
            *reinterpret_cast<uint2*>(usb + byte) = make_uint2(lo, hi);
        }
    }
    __syncthreads();

    bf16x8 b2frag[4];
#pragma unroll
    for (int kt = 0; kt < 4; ++kt)
        b2frag[kt] = *reinterpret_cast<const bf16x8*>(
            w2b + (w * 16 + r16) * MLP_HID + kt * 32 + g4 * 8);

    const int o = w * 16 + r16;
    const float bias = b2[o];
    int gprev = -2;
    float run = 0.f;
#pragma unroll
    for (int mt = 0; mt < 8; ++mt) {
        f32x4 acc2 = (f32x4){0.f, 0.f, 0.f, 0.f};
#pragma unroll
        for (int kt = 0; kt < 4; ++kt) {
            int node = mt * 16 + r16;
            int byte = (node * 256 + (kt * 32 + g4 * 8) * 2) ^ ((node & 7) << 4);
            bf16x8 af = *reinterpret_cast<const bf16x8*>(usb + byte);
            acc2 = __builtin_amdgcn_mfma_f32_16x16x32_bf16(af, b2frag[kt], acc2, 0, 0, 0);
        }
#pragma unroll
        for (int r = 0; r < 4; ++r) {
            int node = mt * 16 + g4 * 4 + r;
            int gn = base + node;
            float v = fmaxf(acc2[r] + bias, 0.f);
            if (write_h && gn < N_NODES) h[(size_t)gn * HID + o] = f2bf(v);
            int gb = sbatch[node];
            if (gb != gprev) {
                if (gprev >= 0) atomicAdd(&out[gprev * 256 + out_col + o], run);
                run = 0.f;
                gprev = gb;
            }
            if (gb >= 0) run += v;
        }
    }
    if (gprev >= 0) atomicAdd(&out[gprev * 256 + out_col + o], run);
}

// ---------------------------------------------------------------------------
extern "C" void kernel_launch(void* const* d_in, const int* in_sizes, int n_in,
                              void* d_out, int out_size, void* d_ws, size_t ws_size,
                              hipStream_t stream)
{
    const int*   x        = (const int*)d_in[0];
    const int*   ei       = (const int*)d_in[1];
    const int*   ea       = (const int*)d_in[2];
    const int*   batch    = (const int*)d_in[3];
    const float* atom_emb = (const float*)d_in[4];
    const float* edge_emb = (const float*)d_in[5];
    const float* w1       = (const float*)d_in[6];
    const float* b1       = (const float*)d_in[7];
    const float* bn_g     = (const float*)d_in[8];
    const float* bn_b     = (const float*)d_in[9];
    const float* bn_m     = (const float*)d_in[10];
    const float* bn_v     = (const float*)d_in[11];
    const float* w2       = (const float*)d_in[12];
    const float* b2       = (const float*)d_in[13];
    const float* eps      = (const float*)d_in[14];

    float* out = (float*)d_out;

    // workspace layout (all chunks 16B-aligned)
    const size_t NODE_PAD = 100096;
    char* ws = (char*)d_ws;
    unsigned short* h     = (unsigned short*)ws; ws += NODE_PAD * HID * 2;            // 12.8 MB
    unsigned short* zbuf  = (unsigned short*)ws; ws += NODE_PAD * HID * 2;            // 12.8 MB
    float* comb           = (float*)ws;          ws += (size_t)3 * N_COMBO * HID * 4; // 203 KB
    unsigned short* w1b   = (unsigned short*)ws; ws += (size_t)3 * MLP_HID * HID * 2;
    unsigned short* w2b   = (unsigned short*)ws; ws += (size_t)3 * HID * MLP_HID * 2;
    float* alpha          = (float*)ws;          ws += (size_t)3 * MLP_HID * 4;
    float* betab          = (float*)ws;          ws += (size_t)3 * MLP_HID * 4;
    int*   cnt            = (int*)ws;            ws += (size_t)N_NODES * 4;
    int*   off            = (int*)ws;            ws += (size_t)N_NODES * 4;
    int*   bcur           = (int*)ws;            ws += 128 * 4;
    unsigned long long* ebuf = (unsigned long long*)ws; ws += (size_t)NBUCK * BCAP * 8; // 16.1 MB
    int*   csr_e          = (int*)ws;            ws += (size_t)NBUCK * BCAP * 4;      // 8.0 MB

    const int nblk128 = (N_NODES + 127) / 128;   // 782

    zero_kernel<<<257, 256, 0, stream>>>(out, bcur);

    misc_kernel<<<NB_EMBED + NB_PREP + NB_SCAT, 256, 0, stream>>>(
        x, atom_emb, batch, h, out,
        edge_emb, w1, w2, b1, bn_g, bn_b, bn_m, bn_v,
        comb, w1b, w2b, alpha, betab,
        ei, ea, bcur, ebuf);

    csr_build_kernel<<<NBUCK, 256, 0, stream>>>(ebuf, bcur, cnt, off, csr_e);

    for (int l = 0; l < 3; ++l) {
        gather_kernel<<<N_NODES / 32, 256, 0, stream>>>(
            cnt, off, csr_e, h, comb + (size_t)l * N_COMBO * HID, eps + l, zbuf);
        mlp_kernel<<<nblk128, 256, 0, stream>>>(
            zbuf, h,
            w1b + (size_t)l * MLP_HID * HID, w2b + (size_t)l * HID * MLP_HID,
            alpha + (size_t)l * MLP_HID, betab + (size_t)l * MLP_HID,
            b2 + (size_t)l * HID, batch, out, (l + 1) * HID, (l < 2) ? 1 : 0);
    }
}

// Round 20
// 244.564 us; speedup vs baseline: 2.2501x; 1.0735x over previous
//
#include <hip/hip_runtime.h>

#define N_NODES 100000
#define N_EDGES 1600000
#define N_GRAPHS 1024
#define HID 64
#define MLP_HID 128
#define N_COMBO 264    // 22*6*2 edge-attr combinations
#define NBUCK 98       // ceil(N_NODES / 1024)
#define BCAP 20480     // fixed bucket capacity (mean 16384)
#define CHUNK 4096     // edges per bscatter block (32KB LDS staging)

#define NB_EMBED 1563  // (N_NODES+63)/64
#define NPREP (3*N_COMBO*HID + 3*MLP_HID*HID + 3*MLP_HID)   // 75648
#define NB_PREP 296    // ceil(NPREP/256)
#define NB_SCAT 391    // ceil(N_EDGES/CHUNK)

typedef __attribute__((ext_vector_type(8))) short bf16x8;
typedef __attribute__((ext_vector_type(4))) float f32x4;
typedef __attribute__((ext_vector_type(2))) float f32x2;

static __device__ __forceinline__ float bf2f(unsigned short u) {
    union { unsigned int i; float f; } v; v.i = ((unsigned int)u) << 16; return v.f;
}
static __device__ __forceinline__ unsigned short f2bf(float f) {
    union { float f; unsigned int i; } v; v.f = f;
    unsigned int u = v.i;
    unsigned int r = u + 0x7FFFu + ((u >> 16) & 1u);   // RNE
    return (unsigned short)(r >> 16);
}
static __device__ __forceinline__ f32x2 bfpair(unsigned int u) {
    union { unsigned int i; float f; } lo, hi;
    lo.i = u << 16;
    hi.i = u & 0xFFFF0000u;
    f32x2 r; r.x = lo.f; r.y = hi.f; return r;
}
static __device__ __forceinline__ unsigned int pack2bf(float a, float b) {
    return (unsigned int)f2bf(a) | ((unsigned int)f2bf(b) << 16);
}

// ---------------------------------------------------------------------------
// zero_kernel: blocks 0..255 zero out (1 float4/thread); block 256 zeros bcur.
// ---------------------------------------------------------------------------
__global__ __launch_bounds__(256) void zero_kernel(
    float* __restrict__ out, int* __restrict__ bcur)
{
    int bid = blockIdx.x;
    int tid = threadIdx.x;
    if (bid < 256) {
        int i = (bid * 256 + tid) * 4;           // 256*256*4 = 262144 floats
        *reinterpret_cast<float4*>(out + i) = make_float4(0.f, 0.f, 0.f, 0.f);
    } else {
        if (tid < 128) bcur[tid] = 0;
    }
}

// ---------------------------------------------------------------------------
// Fused misc kernel: [0,NB_EMBED) atom-embed + pooled[0];
//                    [NB_EMBED, +NB_PREP) weight/comb prep (comb = bf16);
//                    [+, +NB_SCAT) bucket-scatter chunks.
// edge record = (src | combo<<17) | dst<<32  (as u64)
// ---------------------------------------------------------------------------
__global__ __launch_bounds__(256) void misc_kernel(
    const int* __restrict__ x, const float* __restrict__ atom_emb,
    const int* __restrict__ batch, unsigned short* __restrict__ h,
    float* __restrict__ out,
    const float* __restrict__ edge_emb,
    const float* __restrict__ w1, const float* __restrict__ w2,
    const float* __restrict__ b1, const float* __restrict__ bn_g,
    const float* __restrict__ bn_b, const float* __restrict__ bn_m,
    const float* __restrict__ bn_v,
    unsigned short* __restrict__ comb,
    unsigned short* __restrict__ w1b, unsigned short* __restrict__ w2b,
    float* __restrict__ alpha, float* __restrict__ beta,
    const int* __restrict__ ei, const int* __restrict__ ea,
    int* __restrict__ bcur, unsigned long long* __restrict__ ebuf)
{
    __shared__ unsigned long long stage[CHUNK];   // 32 KB (bscatter blocks only)
    __shared__ int hist[NBUCK];
    __shared__ int lbase[NBUCK];
    __shared__ int shift[NBUCK];
    __shared__ int sbuf[128];

    const int bid = blockIdx.x;
    const int tid = threadIdx.x;

    if (bid < NB_EMBED) {
        // ---- atom embedding (9-table sum) + pooled[0]
        int f = tid & 63;
        int q = __builtin_amdgcn_readfirstlane(tid >> 6);   // wave-uniform
        int base = bid * 64 + q * 16;
        float run = 0.f;
        int cg = -1;
        for (int k = 0; k < 16; ++k) {
            int gn = base + k;
            if (gn >= N_NODES) break;
            const int* xp = x + gn * 9;                     // uniform -> s_load
            float acc = 0.f;
#pragma unroll
            for (int j = 0; j < 9; ++j) {
                int idx = xp[j];
                acc += atom_emb[(j * 119 + idx) * HID + f]; // coalesced 256B
            }
            h[(size_t)gn * HID + f] = f2bf(acc);
            int g = batch[gn];                              // uniform
            if (g != cg) {
                if (cg >= 0) atomicAdd(&out[cg * 256 + f], run);
                run = 0.f; cg = g;
            }
            run += acc;
        }
        if (cg >= 0) atomicAdd(&out[cg * 256 + f], run);
    } else if (bid < NB_EMBED + NB_PREP) {
        // ---- prep: bf16 comb table, bf16 weights, folded BN affine
        int t = (bid - NB_EMBED) * 256 + tid;
        const int NC = 3 * N_COMBO * HID;   // 50688
        const int NW = 3 * MLP_HID * HID;   // 24576
        if (t < NC) {
            int d = t & 63;
            int c = (t >> 6) % N_COMBO;
            int l = (t >> 6) / N_COMBO;
            int a0 = c / 12, r = c % 12, a1 = r >> 1, a2 = r & 1;
            const float* base = edge_emb + (size_t)l * 3 * 22 * HID;
            comb[t] = f2bf(base[(0 * 22 + a0) * HID + d]
                         + base[(1 * 22 + a1) * HID + d]
                         + base[(2 * 22 + a2) * HID + d]);
        } else if (t < NC + NW) {
            int i = t - NC;
            w1b[i] = f2bf(w1[i]);
            w2b[i] = f2bf(w2[i]);
        } else if (t < NC + NW + 3 * MLP_HID) {
            int i = t - NC - NW;
            float a = rsqrtf(bn_v[i] + 1e-5f) * bn_g[i];
            alpha[i] = a;
            beta[i] = (b1[i] - bn_m[i]) * a + bn_b[i];
        }
    } else {
        // ---- bscatter chunk: LDS-staged reorder by bucket, coalesced copy-out
        int base = (bid - NB_EMBED - NB_PREP) * CHUNK;
        int n_here = min(CHUNK, N_EDGES - base);

        for (int i = tid; i < NBUCK; i += 256) hist[i] = 0;
        __syncthreads();
        for (int i = tid; i < n_here; i += 256)
            atomicAdd(&hist[ei[N_EDGES + base + i] >> 10], 1);
        __syncthreads();
        if (tid < 128) sbuf[tid] = (tid < NBUCK) ? hist[tid] : 0;
        __syncthreads();
        for (int s = 1; s < 128; s <<= 1) {
            int u = 0;
            if (tid < 128 && tid >= s) u = sbuf[tid - s];
            __syncthreads();
            if (tid < 128) sbuf[tid] += u;
            __syncthreads();
        }
        if (tid < NBUCK) lbase[tid] = sbuf[tid] - hist[tid];
        __syncthreads();
        if (tid < NBUCK) {
            int c = hist[tid];
            if (c > 0) {
                int g = tid * BCAP + atomicAdd(&bcur[tid], c);
                shift[tid] = g - lbase[tid];
            }
            hist[tid] = lbase[tid];
        }
        __syncthreads();
        for (int i = tid; i < n_here; i += 256) {
            int e = base + i;
            int src = ei[e];
            int dst = ei[N_EDGES + e];
            int combo = (ea[e * 3 + 0] * 6 + ea[e * 3 + 1]) * 2 + ea[e * 3 + 2];
            int pos = atomicAdd(&hist[dst >> 10], 1);
            stage[pos] = (unsigned long long)(unsigned)(src | (combo << 17))
                       | ((unsigned long long)(unsigned)dst << 32);
        }
        __syncthreads();
        for (int i = tid; i < n_here; i += 256) {
            unsigned long long en = stage[i];
            ebuf[shift[(int)(en >> 32) >> 10] + i] = en;
        }
    }
}

// ---------------------------------------------------------------------------
// csr_build: one block per bucket; exact per-node CSR within the bucket's
// region [b*BCAP, b*BCAP + bcur[b]); writes global cnt/off.
// ---------------------------------------------------------------------------
__global__ __launch_bounds__(256) void csr_build_kernel(
    const unsigned long long* __restrict__ ebuf, const int* __restrict__ bcur,
    int* __restrict__ cnt, int* __restrict__ off, int* __restrict__ csr_e)
{
    __shared__ int nh[1024];
    __shared__ int cur[1024];
    __shared__ int part[256];

    int b = blockIdx.x;
    int tid = threadIdx.x;
    int nodeBase = b << 10;
    int limit = min(1024, N_NODES - nodeBase);
    int beg = b * BCAP;
    int end = beg + bcur[b];

    for (int i = tid; i < 1024; i += 256) nh[i] = 0;
    __syncthreads();
    for (int i = beg + tid; i < end; i += 256)
        atomicAdd(&nh[(int)(ebuf[i] >> 32) - nodeBase], 1);
    __syncthreads();

    int s0 = nh[tid * 4], s1 = nh[tid * 4 + 1], s2 = nh[tid * 4 + 2], s3 = nh[tid * 4 + 3];
    part[tid] = s0 + s1 + s2 + s3;
    __syncthreads();
    for (int st = 1; st < 256; st <<= 1) {
        int v = 0;
        if (tid >= st) v = part[tid - st];
        __syncthreads();
        if (tid >= st) part[tid] += v;
        __syncthreads();
    }
    int e0 = (tid ? part[tid - 1] : 0);
    int e1 = e0 + s0, e2 = e1 + s1, e3 = e2 + s2;
    cur[tid * 4 + 0] = e0; cur[tid * 4 + 1] = e1;
    cur[tid * 4 + 2] = e2; cur[tid * 4 + 3] = e3;
    int excl[4] = {e0, e1, e2, e3};
    int cval[4] = {s0, s1, s2, s3};
#pragma unroll
    for (int j = 0; j < 4; ++j) {
        int nl = tid * 4 + j;
        if (nl < limit) {
            cnt[nodeBase + nl] = cval[j];
            off[nodeBase + nl] = beg + excl[j];
        }
    }
    __syncthreads();
    for (int i = beg + tid; i < end; i += 256) {
        unsigned long long en = ebuf[i];
        int pos = atomicAdd(&cur[(int)(en >> 32) - nodeBase], 1);
        csr_e[beg + pos] = (int)(unsigned)en;
    }
}

// ---------------------------------------------------------------------------
// Gather: 8-lane group per node (natural order); lane = 8 features.
// bf16 comb: 2 loads/edge-lane (not 3). 2x loop with csr_e pair-prefetch.
// z[n] = relu((1+eps)*h[n] + sum_e relu(h[src] + comb[combo]))  (bf16 out)
// ---------------------------------------------------------------------------
__global__ __launch_bounds__(256, 8) void gather_kernel(
    const int* __restrict__ cnt, const int* __restrict__ off,
    const int* __restrict__ csr_e, const unsigned short* __restrict__ h,
    const unsigned short* __restrict__ comb_l, const float* __restrict__ eps_p,
    unsigned short* __restrict__ zbuf)
{
    const int tid = threadIdx.x;
    const int lane = tid & 63;
    const int grp = lane >> 3;                    // group 0..7 in wave
    const int fo = (lane & 7) << 3;               // 8 features per lane
    const int n = blockIdx.x * 32 + (tid >> 6) * 8 + grp;   // N_NODES%32==0

    const int beg = off[n];
    const int end = beg + cnt[n];

    const f32x2 zero2 = {0.f, 0.f};
    f32x2 a0 = zero2, a1 = zero2, a2 = zero2, a3 = zero2;

#define EDGE_ACC(PK)                                                               \
    {                                                                              \
        int pk_ = (PK);                                                            \
        uint4 hv = *reinterpret_cast<const uint4*>(h + (pk_ & 0x1FFFF) * HID + fo);\
        uint4 ev = *reinterpret_cast<const uint4*>(comb_l + (pk_ >> 17) * HID + fo);\
        a0 += __builtin_elementwise_max(bfpair(hv.x) + bfpair(ev.x), zero2);       \
        a1 += __builtin_elementwise_max(bfpair(hv.y) + bfpair(ev.y), zero2);       \
        a2 += __builtin_elementwise_max(bfpair(hv.z) + bfpair(ev.z), zero2);       \
        a3 += __builtin_elementwise_max(bfpair(hv.w) + bfpair(ev.w), zero2);       \
    }

    int i = beg;
    if (end - beg >= 2) {
        int pk0 = csr_e[i];
        int pk1 = csr_e[i + 1];
        for (; i + 3 < end; i += 2) {
            int nk0 = csr_e[i + 2];       // prefetch next pair
            int nk1 = csr_e[i + 3];
            EDGE_ACC(pk0);
            EDGE_ACC(pk1);
            pk0 = nk0;
            pk1 = nk1;
        }
        EDGE_ACC(pk0);
        EDGE_ACC(pk1);
        i += 2;
    }
    for (; i < end; ++i) EDGE_ACC(csr_e[i]);
#undef EDGE_ACC

    uint4 hn = *reinterpret_cast<const uint4*>(h + (size_t)n * HID + fo);
    float ep1 = 1.0f + eps_p[0];
    f32x2 ep2 = {ep1, ep1};
    f32x2 z0 = __builtin_elementwise_max(ep2 * bfpair(hn.x) + a0, zero2);
    f32x2 z1 = __builtin_elementwise_max(ep2 * bfpair(hn.y) + a1, zero2);
    f32x2 z2 = __builtin_elementwise_max(ep2 * bfpair(hn.z) + a2, zero2);
    f32x2 z3 = __builtin_elementwise_max(ep2 * bfpair(hn.w) + a3, zero2);
    uint4 o;
    o.x = pack2bf(z0.x, z0.y);
    o.y = pack2bf(z1.x, z1.y);
    o.z = pack2bf(z2.x, z2.y);
    o.w = pack2bf(z3.x, z3.y);
    *reinterpret_cast<uint4*>(zbuf + (size_t)n * HID + fo) = o;
}

// ---------------------------------------------------------------------------
// MFMA node MLP, 128-node tiles.
// ---------------------------------------------------------------------------
__global__ __launch_bounds__(256) void mlp_kernel(
    const unsigned short* __restrict__ zbuf, unsigned short* __restrict__ h,
    const unsigned short* __restrict__ w1b, const unsigned short* __restrict__ w2b,
    const float* __restrict__ alpha, const float* __restrict__ beta,
    const float* __restrict__ b2, const int* __restrict__ batch,
    float* __restrict__ out, int out_col, int write_h)
{
    __shared__ unsigned short us[128 * MLP_HID];   // 32 KB
    __shared__ int sbatch[128];

    const int tid = threadIdx.x;
    const int lane = tid & 63;
    const int w = __builtin_amdgcn_readfirstlane(tid >> 6);
    const int base = blockIdx.x * 128;
    const int r16 = lane & 15;
    const int g4 = lane >> 4;                     // 0..3

    if (tid < 128) sbatch[tid] = (base + tid < N_NODES) ? batch[base + tid] : -1;

    bf16x8 awf[2][2];
#pragma unroll
    for (int mo = 0; mo < 2; ++mo)
#pragma unroll
        for (int kt = 0; kt < 2; ++kt) {
            int o = (2 * w + mo) * 16 + r16;
            awf[mo][kt] = *reinterpret_cast<const bf16x8*>(w1b + o * HID + kt * 32 + g4 * 8);
        }
    float4 al[2], be[2];
#pragma unroll
    for (int mo = 0; mo < 2; ++mo) {
        int o0 = (2 * w + mo) * 16 + g4 * 4;
        al[mo] = *reinterpret_cast<const float4*>(alpha + o0);
        be[mo] = *reinterpret_cast<const float4*>(beta + o0);
    }

    char* usb = (char*)us;
#pragma unroll
    for (int nt = 0; nt < 8; ++nt) {
        bf16x8 zf[2];
#pragma unroll
        for (int kt = 0; kt < 2; ++kt)
            zf[kt] = *reinterpret_cast<const bf16x8*>(
                zbuf + (size_t)(base + nt * 16 + r16) * HID + kt * 32 + g4 * 8);
        f32x4 acc[2] = {(f32x4){0.f, 0.f, 0.f, 0.f}, (f32x4){0.f, 0.f, 0.f, 0.f}};
#pragma unroll
        for (int mo = 0; mo < 2; ++mo)
#pragma unroll
            for (int kt = 0; kt < 2; ++kt)
                acc[mo] = __builtin_amdgcn_mfma_f32_16x16x32_bf16(
                    awf[mo][kt], zf[kt], acc[mo], 0, 0, 0);
        int node = nt * 16 + r16;
#pragma unroll
        for (int mo = 0; mo < 2; ++mo) {
            int o0 = (2 * w + mo) * 16 + g4 * 4;
            f32x4 a = acc[mo];
            unsigned lo = pack2bf(fmaxf(a[0] * al[mo].x + be[mo].x, 0.f),
                                  fmaxf(a[1] * al[mo].y + be[mo].y, 0.f));
            unsigned hi = pack2bf(fmaxf(a[2] * al[mo].z + be[mo].z, 0.f),
                                  fmaxf(a[3] * al[mo].w + be[mo].w, 0.f));
            int byte = (node * 256 + o0 * 2) ^ ((node & 7) << 4);
            *reinterpret_cast<uint2*>(usb + byte) = make_uint2(lo, hi);
        }
    }
    __syncthreads();

    bf16x8 b2frag[4];
#pragma unroll
    for (int kt = 0; kt < 4; ++kt)
        b2frag[kt] = *reinterpret_cast<const bf16x8*>(
            w2b + (w * 16 + r16) * MLP_HID + kt * 32 + g4 * 8);

    const int o = w * 16 + r16;
    const float bias = b2[o];
    int gprev = -2;
    float run = 0.f;
#pragma unroll
    for (int mt = 0; mt < 8; ++mt) {
        f32x4 acc2 = (f32x4){0.f, 0.f, 0.f, 0.f};
#pragma unroll
        for (int kt = 0; kt < 4; ++kt) {
            int node = mt * 16 + r16;
            int byte = (node * 256 + (kt * 32 + g4 * 8) * 2) ^ ((node & 7) << 4);
            bf16x8 af = *reinterpret_cast<const bf16x8*>(usb + byte);
            acc2 = __builtin_amdgcn_mfma_f32_16x16x32_bf16(af, b2frag[kt], acc2, 0, 0, 0);
        }
#pragma unroll
        for (int r = 0; r < 4; ++r) {
            int node = mt * 16 + g4 * 4 + r;
            int gn = base + node;
            float v = fmaxf(acc2[r] + bias, 0.f);
            if (write_h && gn < N_NODES) h[(size_t)gn * HID + o] = f2bf(v);
            int gb = sbatch[node];
            if (gb != gprev) {
                if (gprev >= 0) atomicAdd(&out[gprev * 256 + out_col + o], run);
                run = 0.f;
                gprev = gb;
            }
            if (gb >= 0) run += v;
        }
    }
    if (gprev >= 0) atomicAdd(&out[gprev * 256 + out_col + o], run);
}

// ---------------------------------------------------------------------------
extern "C" void kernel_launch(void* const* d_in, const int* in_sizes, int n_in,
                              void* d_out, int out_size, void* d_ws, size_t ws_size,
                              hipStream_t stream)
{
    const int*   x        = (const int*)d_in[0];
    const int*   ei       = (const int*)d_in[1];
    const int*   ea       = (const int*)d_in[2];
    const int*   batch    = (const int*)d_in[3];
    const float* atom_emb = (const float*)d_in[4];
    const float* edge_emb = (const float*)d_in[5];
    const float* w1       = (const float*)d_in[6];
    const float* b1       = (const float*)d_in[7];
    const float* bn_g     = (const float*)d_in[8];
    const float* bn_b     = (const float*)d_in[9];
    const float* bn_m     = (const float*)d_in[10];
    const float* bn_v     = (const float*)d_in[11];
    const float* w2       = (const float*)d_in[12];
    const float* b2       = (const float*)d_in[13];
    const float* eps      = (const float*)d_in[14];

    float* out = (float*)d_out;

    // workspace layout (all chunks 16B-aligned)
    const size_t NODE_PAD = 100096;
    char* ws = (char*)d_ws;
    unsigned short* h     = (unsigned short*)ws; ws += NODE_PAD * HID * 2;            // 12.8 MB
    unsigned short* zbuf  = (unsigned short*)ws; ws += NODE_PAD * HID * 2;            // 12.8 MB
    unsigned short* comb  = (unsigned short*)ws; ws += (size_t)3 * N_COMBO * HID * 2; // 101 KB
    unsigned short* w1b   = (unsigned short*)ws; ws += (size_t)3 * MLP_HID * HID * 2;
    unsigned short* w2b   = (unsigned short*)ws; ws += (size_t)3 * HID * MLP_HID * 2;
    float* alpha          = (float*)ws;          ws += (size_t)3 * MLP_HID * 4;
    float* betab          = (float*)ws;          ws += (size_t)3 * MLP_HID * 4;
    int*   cnt            = (int*)ws;            ws += (size_t)N_NODES * 4;
    int*   off            = (int*)ws;            ws += (size_t)N_NODES * 4;
    int*   bcur           = (int*)ws;            ws += 128 * 4;
    unsigned long long* ebuf = (unsigned long long*)ws; ws += (size_t)NBUCK * BCAP * 8; // 16.1 MB
    int*   csr_e          = (int*)ws;            ws += (size_t)NBUCK * BCAP * 4;      // 8.0 MB

    const int nblk128 = (N_NODES + 127) / 128;   // 782

    zero_kernel<<<257, 256, 0, stream>>>(out, bcur);

    misc_kernel<<<NB_EMBED + NB_PREP + NB_SCAT, 256, 0, stream>>>(
        x, atom_emb, batch, h, out,
        edge_emb, w1, w2, b1, bn_g, bn_b, bn_m, bn_v,
        comb, w1b, w2b, alpha, betab,
        ei, ea, bcur, ebuf);

    csr_build_kernel<<<NBUCK, 256, 0, stream>>>(ebuf, bcur, cnt, off, csr_e);

    for (int l = 0; l < 3; ++l) {
        gather_kernel<<<N_NODES / 32, 256, 0, stream>>>(
            cnt, off, csr_e, h, comb + (size_t)l * N_COMBO * HID, eps + l, zbuf);
        mlp_kernel<<<nblk128, 256, 0, stream>>>(
            zbuf, h,
            w1b + (size_t)l * MLP_HID * HID, w2b + (size_t)l * HID * MLP_HID,
            alpha + (size_t)l * MLP_HID, betab + (size_t)l * MLP_HID,
            b2 + (size_t)l * HID, batch, out, (l + 1) * HID, (l < 2) ? 1 : 0);
    }
}

// Round 21
// 242.464 us; speedup vs baseline: 2.2696x; 1.0087x over previous
//
#include <hip/hip_runtime.h>

#define N_NODES 100000
#define N_EDGES 1600000
#define N_GRAPHS 1024
#define HID 64
#define MLP_HID 128
#define N_COMBO 264    // 22*6*2 edge-attr combinations
#define NBUCK 98       // ceil(N_NODES / 1024)
#define BCAP 20480     // fixed bucket capacity (mean 16384)
#define CHUNK 2048     // edges per bscatter block (16KB LDS staging -> 8 blk/CU)

#define NB_EMBED 1563  // (N_NODES+63)/64
#define NPREP (3*N_COMBO*HID + 3*MLP_HID*HID + 3*MLP_HID)   // 75648
#define NB_PREP 296    // ceil(NPREP/256)
#define NB_SCAT 782    // ceil(N_EDGES/CHUNK)

typedef __attribute__((ext_vector_type(8))) short bf16x8;
typedef __attribute__((ext_vector_type(4))) float f32x4;
typedef __attribute__((ext_vector_type(2))) float f32x2;

static __device__ __forceinline__ float bf2f(unsigned short u) {
    union { unsigned int i; float f; } v; v.i = ((unsigned int)u) << 16; return v.f;
}
static __device__ __forceinline__ unsigned short f2bf(float f) {
    union { float f; unsigned int i; } v; v.f = f;
    unsigned int u = v.i;
    unsigned int r = u + 0x7FFFu + ((u >> 16) & 1u);   // RNE
    return (unsigned short)(r >> 16);
}
static __device__ __forceinline__ f32x2 bfpair(unsigned int u) {
    union { unsigned int i; float f; } lo, hi;
    lo.i = u << 16;
    hi.i = u & 0xFFFF0000u;
    f32x2 r; r.x = lo.f; r.y = hi.f; return r;
}
static __device__ __forceinline__ unsigned int pack2bf(float a, float b) {
    return (unsigned int)f2bf(a) | ((unsigned int)f2bf(b) << 16);
}

// ---------------------------------------------------------------------------
// zero_kernel: blocks 0..255 zero out (1 float4/thread); block 256 zeros bcur.
// ---------------------------------------------------------------------------
__global__ __launch_bounds__(256) void zero_kernel(
    float* __restrict__ out, int* __restrict__ bcur)
{
    int bid = blockIdx.x;
    int tid = threadIdx.x;
    if (bid < 256) {
        int i = (bid * 256 + tid) * 4;           // 256*256*4 = 262144 floats
        *reinterpret_cast<float4*>(out + i) = make_float4(0.f, 0.f, 0.f, 0.f);
    } else {
        if (tid < 128) bcur[tid] = 0;
    }
}

// ---------------------------------------------------------------------------
// Fused misc kernel: [0,NB_EMBED) atom-embed + pooled[0];
//                    [NB_EMBED, +NB_PREP) weight/comb prep (comb = bf16);
//                    [+, +NB_SCAT) bucket-scatter chunks.
// edge record = (src | combo<<17) | dst<<32  (as u64)
// ---------------------------------------------------------------------------
__global__ __launch_bounds__(256) void misc_kernel(
    const int* __restrict__ x, const float* __restrict__ atom_emb,
    const int* __restrict__ batch, unsigned short* __restrict__ h,
    float* __restrict__ out,
    const float* __restrict__ edge_emb,
    const float* __restrict__ w1, const float* __restrict__ w2,
    const float* __restrict__ b1, const float* __restrict__ bn_g,
    const float* __restrict__ bn_b, const float* __restrict__ bn_m,
    const float* __restrict__ bn_v,
    unsigned short* __restrict__ comb,
    unsigned short* __restrict__ w1b, unsigned short* __restrict__ w2b,
    float* __restrict__ alpha, float* __restrict__ beta,
    const int* __restrict__ ei, const int* __restrict__ ea,
    int* __restrict__ bcur, unsigned long long* __restrict__ ebuf)
{
    __shared__ unsigned long long stage[CHUNK];   // 16 KB (bscatter blocks only)
    __shared__ int hist[NBUCK];
    __shared__ int lbase[NBUCK];
    __shared__ int shift[NBUCK];
    __shared__ int sbuf[128];

    const int bid = blockIdx.x;
    const int tid = threadIdx.x;

    if (bid < NB_EMBED) {
        // ---- atom embedding (9-table sum) + pooled[0]
        int f = tid & 63;
        int q = __builtin_amdgcn_readfirstlane(tid >> 6);   // wave-uniform
        int base = bid * 64 + q * 16;
        float run = 0.f;
        int cg = -1;
        for (int k = 0; k < 16; ++k) {
            int gn = base + k;
            if (gn >= N_NODES) break;
            const int* xp = x + gn * 9;                     // uniform -> s_load
            float acc = 0.f;
#pragma unroll
            for (int j = 0; j < 9; ++j) {
                int idx = xp[j];
                acc += atom_emb[(j * 119 + idx) * HID + f]; // coalesced 256B
            }
            h[(size_t)gn * HID + f] = f2bf(acc);
            int g = batch[gn];                              // uniform
            if (g != cg) {
                if (cg >= 0) atomicAdd(&out[cg * 256 + f], run);
                run = 0.f; cg = g;
            }
            run += acc;
        }
        if (cg >= 0) atomicAdd(&out[cg * 256 + f], run);
    } else if (bid < NB_EMBED + NB_PREP) {
        // ---- prep: bf16 comb table, bf16 weights, folded BN affine
        int t = (bid - NB_EMBED) * 256 + tid;
        const int NC = 3 * N_COMBO * HID;   // 50688
        const int NW = 3 * MLP_HID * HID;   // 24576
        if (t < NC) {
            int d = t & 63;
            int c = (t >> 6) % N_COMBO;
            int l = (t >> 6) / N_COMBO;
            int a0 = c / 12, r = c % 12, a1 = r >> 1, a2 = r & 1;
            const float* base = edge_emb + (size_t)l * 3 * 22 * HID;
            comb[t] = f2bf(base[(0 * 22 + a0) * HID + d]
                         + base[(1 * 22 + a1) * HID + d]
                         + base[(2 * 22 + a2) * HID + d]);
        } else if (t < NC + NW) {
            int i = t - NC;
            w1b[i] = f2bf(w1[i]);
            w2b[i] = f2bf(w2[i]);
        } else if (t < NC + NW + 3 * MLP_HID) {
            int i = t - NC - NW;
            float a = rsqrtf(bn_v[i] + 1e-5f) * bn_g[i];
            alpha[i] = a;
            beta[i] = (b1[i] - bn_m[i]) * a + bn_b[i];
        }
    } else {
        // ---- bscatter chunk: LDS-staged reorder by bucket, coalesced copy-out
        int base = (bid - NB_EMBED - NB_PREP) * CHUNK;
        int n_here = min(CHUNK, N_EDGES - base);

        for (int i = tid; i < NBUCK; i += 256) hist[i] = 0;
        __syncthreads();
        for (int i = tid; i < n_here; i += 256)
            atomicAdd(&hist[ei[N_EDGES + base + i] >> 10], 1);
        __syncthreads();
        if (tid < 128) sbuf[tid] = (tid < NBUCK) ? hist[tid] : 0;
        __syncthreads();
        for (int s = 1; s < 128; s <<= 1) {
            int u = 0;
            if (tid < 128 && tid >= s) u = sbuf[tid - s];
            __syncthreads();
            if (tid < 128) sbuf[tid] += u;
            __syncthreads();
        }
        if (tid < NBUCK) lbase[tid] = sbuf[tid] - hist[tid];
        __syncthreads();
        if (tid < NBUCK) {
            int c = hist[tid];
            if (c > 0) {
                int g = tid * BCAP + atomicAdd(&bcur[tid], c);
                shift[tid] = g - lbase[tid];
            }
            hist[tid] = lbase[tid];
        }
        __syncthreads();
        for (int i = tid; i < n_here; i += 256) {
            int e = base + i;
            int src = ei[e];
            int dst = ei[N_EDGES + e];
            int combo = (ea[e * 3 + 0] * 6 + ea[e * 3 + 1]) * 2 + ea[e * 3 + 2];
            int pos = atomicAdd(&hist[dst >> 10], 1);
            stage[pos] = (unsigned long long)(unsigned)(src | (combo << 17))
                       | ((unsigned long long)(unsigned)dst << 32);
        }
        __syncthreads();
        for (int i = tid; i < n_here; i += 256) {
            unsigned long long en = stage[i];
            ebuf[shift[(int)(en >> 32) >> 10] + i] = en;
        }
    }
}

// ---------------------------------------------------------------------------
// csr_build: one block per bucket; exact per-node CSR within the bucket's
// region [b*BCAP, b*BCAP + bcur[b]); writes global cnt/off.
// ---------------------------------------------------------------------------
__global__ __launch_bounds__(256) void csr_build_kernel(
    const unsigned long long* __restrict__ ebuf, const int* __restrict__ bcur,
    int* __restrict__ cnt, int* __restrict__ off, int* __restrict__ csr_e)
{
    __shared__ int nh[1024];
    __shared__ int cur[1024];
    __shared__ int part[256];

    int b = blockIdx.x;
    int tid = threadIdx.x;
    int nodeBase = b << 10;
    int limit = min(1024, N_NODES - nodeBase);
    int beg = b * BCAP;
    int end = beg + bcur[b];

    for (int i = tid; i < 1024; i += 256) nh[i] = 0;
    __syncthreads();
    for (int i = beg + tid; i < end; i += 256)
        atomicAdd(&nh[(int)(ebuf[i] >> 32) - nodeBase], 1);
    __syncthreads();

    int s0 = nh[tid * 4], s1 = nh[tid * 4 + 1], s2 = nh[tid * 4 + 2], s3 = nh[tid * 4 + 3];
    part[tid] = s0 + s1 + s2 + s3;
    __syncthreads();
    for (int st = 1; st < 256; st <<= 1) {
        int v = 0;
        if (tid >= st) v = part[tid - st];
        __syncthreads();
        if (tid >= st) part[tid] += v;
        __syncthreads();
    }
    int e0 = (tid ? part[tid - 1] : 0);
    int e1 = e0 + s0, e2 = e1 + s1, e3 = e2 + s2;
    cur[tid * 4 + 0] = e0; cur[tid * 4 + 1] = e1;
    cur[tid * 4 + 2] = e2; cur[tid * 4 + 3] = e3;
    int excl[4] = {e0, e1, e2, e3};
    int cval[4] = {s0, s1, s2, s3};
#pragma unroll
    for (int j = 0; j < 4; ++j) {
        int nl = tid * 4 + j;
        if (nl < limit) {
            cnt[nodeBase + nl] = cval[j];
            off[nodeBase + nl] = beg + excl[j];
        }
    }
    __syncthreads();
    for (int i = beg + tid; i < end; i += 256) {
        unsigned long long en = ebuf[i];
        int pos = atomicAdd(&cur[(int)(en >> 32) - nodeBase], 1);
        csr_e[beg + pos] = (int)(unsigned)en;
    }
}

// ---------------------------------------------------------------------------
// Gather: 8-lane group per node (natural order); lane = 8 features.
// bf16 comb: 2 loads/edge-lane. 2x loop with csr_e pair-prefetch.
// z[n] = relu((1+eps)*h[n] + sum_e relu(h[src] + comb[combo]))  (bf16 out)
// ---------------------------------------------------------------------------
__global__ __launch_bounds__(256, 8) void gather_kernel(
    const int* __restrict__ cnt, const int* __restrict__ off,
    const int* __restrict__ csr_e, const unsigned short* __restrict__ h,
    const unsigned short* __restrict__ comb_l, const float* __restrict__ eps_p,
    unsigned short* __restrict__ zbuf)
{
    const int tid = threadIdx.x;
    const int lane = tid & 63;
    const int grp = lane >> 3;                    // group 0..7 in wave
    const int fo = (lane & 7) << 3;               // 8 features per lane
    const int n = blockIdx.x * 32 + (tid >> 6) * 8 + grp;   // N_NODES%32==0

    const int beg = off[n];
    const int end = beg + cnt[n];

    const f32x2 zero2 = {0.f, 0.f};
    f32x2 a0 = zero2, a1 = zero2, a2 = zero2, a3 = zero2;

#define EDGE_ACC(PK)                                                               \
    {                                                                              \
        int pk_ = (PK);                                                            \
        uint4 hv = *reinterpret_cast<const uint4*>(h + (pk_ & 0x1FFFF) * HID + fo);\
        uint4 ev = *reinterpret_cast<const uint4*>(comb_l + (pk_ >> 17) * HID + fo);\
        a0 += __builtin_elementwise_max(bfpair(hv.x) + bfpair(ev.x), zero2);       \
        a1 += __builtin_elementwise_max(bfpair(hv.y) + bfpair(ev.y), zero2);       \
        a2 += __builtin_elementwise_max(bfpair(hv.z) + bfpair(ev.z), zero2);       \
        a3 += __builtin_elementwise_max(bfpair(hv.w) + bfpair(ev.w), zero2);       \
    }

    int i = beg;
    if (end - beg >= 2) {
        int pk0 = csr_e[i];
        int pk1 = csr_e[i + 1];
        for (; i + 3 < end; i += 2) {
            int nk0 = csr_e[i + 2];       // prefetch next pair
            int nk1 = csr_e[i + 3];
            EDGE_ACC(pk0);
            EDGE_ACC(pk1);
            pk0 = nk0;
            pk1 = nk1;
        }
        EDGE_ACC(pk0);
        EDGE_ACC(pk1);
        i += 2;
    }
    for (; i < end; ++i) EDGE_ACC(csr_e[i]);
#undef EDGE_ACC

    uint4 hn = *reinterpret_cast<const uint4*>(h + (size_t)n * HID + fo);
    float ep1 = 1.0f + eps_p[0];
    f32x2 ep2 = {ep1, ep1};
    f32x2 z0 = __builtin_elementwise_max(ep2 * bfpair(hn.x) + a0, zero2);
    f32x2 z1 = __builtin_elementwise_max(ep2 * bfpair(hn.y) + a1, zero2);
    f32x2 z2 = __builtin_elementwise_max(ep2 * bfpair(hn.z) + a2, zero2);
    f32x2 z3 = __builtin_elementwise_max(ep2 * bfpair(hn.w) + a3, zero2);
    uint4 o;
    o.x = pack2bf(z0.x, z0.y);
    o.y = pack2bf(z1.x, z1.y);
    o.z = pack2bf(z2.x, z2.y);
    o.w = pack2bf(z3.x, z3.y);
    *reinterpret_cast<uint4*>(zbuf + (size_t)n * HID + fo) = o;
}

// ---------------------------------------------------------------------------
// MFMA node MLP, 128-node tiles.
// ---------------------------------------------------------------------------
__global__ __launch_bounds__(256) void mlp_kernel(
    const unsigned short* __restrict__ zbuf, unsigned short* __restrict__ h,
    const unsigned short* __restrict__ w1b, const unsigned short* __restrict__ w2b,
    const float* __restrict__ alpha, const float* __restrict__ beta,
    const float* __restrict__ b2, const int* __restrict__ batch,
    float* __restrict__ out, int out_col, int write_h)
{
    __shared__ unsigned short us[128 * MLP_HID];   // 32 KB
    __shared__ int sbatch[128];

    const int tid = threadIdx.x;
    const int lane = tid & 63;
    const int w = __builtin_amdgcn_readfirstlane(tid >> 6);
    const int base = blockIdx.x * 128;
    const int r16 = lane & 15;
    const int g4 = lane >> 4;                     // 0..3

    if (tid < 128) sbatch[tid] = (base + tid < N_NODES) ? batch[base + tid] : -1;

    bf16x8 awf[2][2];
#pragma unroll
    for (int mo = 0; mo < 2; ++mo)
#pragma unroll
        for (int kt = 0; kt < 2; ++kt) {
            int o = (2 * w + mo) * 16 + r16;
            awf[mo][kt] = *reinterpret_cast<const bf16x8*>(w1b + o * HID + kt * 32 + g4 * 8);
        }
    float4 al[2], be[2];
#pragma unroll
    for (int mo = 0; mo < 2; ++mo) {
        int o0 = (2 * w + mo) * 16 + g4 * 4;
        al[mo] = *reinterpret_cast<const float4*>(alpha + o0);
        be[mo] = *reinterpret_cast<const float4*>(beta + o0);
    }

    char* usb = (char*)us;
#pragma unroll
    for (int nt = 0; nt < 8; ++nt) {
        bf16x8 zf[2];
#pragma unroll
        for (int kt = 0; kt < 2; ++kt)
            zf[kt] = *reinterpret_cast<const bf16x8*>(
                zbuf + (size_t)(base + nt * 16 + r16) * HID + kt * 32 + g4 * 8);
        f32x4 acc[2] = {(f32x4){0.f, 0.f, 0.f, 0.f}, (f32x4){0.f, 0.f, 0.f, 0.f}};
#pragma unroll
        for (int mo = 0; mo < 2; ++mo)
#pragma unroll
            for (int kt = 0; kt < 2; ++kt)
                acc[mo] = __builtin_amdgcn_mfma_f32_16x16x32_bf16(
                    awf[mo][kt], zf[kt], acc[mo], 0, 0, 0);
        int node = nt * 16 + r16;
#pragma unroll
        for (int mo = 0; mo < 2; ++mo) {
            int o0 = (2 * w + mo) * 16 + g4 * 4;
            f32x4 a = acc[mo];
            unsigned lo = pack2bf(fmaxf(a[0] * al[mo].x + be[mo].x, 0.f),
                                  fmaxf(a[1] * al[mo].y + be[mo].y, 0.f));
            unsigned hi = pack2bf(fmaxf(a[2] * al[mo].z + be[mo].z, 0.f),
                                  fmaxf(a[3] * al[mo].w + be[mo].w, 0.f));
            int byte = (node * 256 + o0 * 2) ^ ((node & 7) << 4);
            *reinterpret_cast<uint2*>(usb + byte) = make_uint2(lo, hi);
        }
    }
    __syncthreads();

    bf16x8 b2frag[4];
#pragma unroll
    for (int kt = 0; kt < 4; ++kt)
        b2frag[kt] = *reinterpret_cast<const bf16x8*>(
            w2b + (w * 16 + r16) * MLP_HID + kt * 32 + g4 * 8);

    const int o = w * 16 + r16;
    const float bias = b2[o];
    int gprev = -2;
    float run = 0.f;
#pragma unroll
    for (int mt = 0; mt < 8; ++mt) {
        f32x4 acc2 = (f32x4){0.f, 0.f, 0.f, 0.f};
#pragma unroll
        for (int kt = 0; kt < 4; ++kt) {
            int node = mt * 16 + r16;
            int byte = (node * 256 + (kt * 32 + g4 * 8) * 2) ^ ((node & 7) << 4);
            bf16x8 af = *reinterpret_cast<const bf16x8*>(usb + byte);
            acc2 = __builtin_amdgcn_mfma_f32_16x16x32_bf16(af, b2frag[kt], acc2, 0, 0, 0);
        }
#pragma unroll
        for (int r = 0; r < 4; ++r) {
            int node = mt * 16 + g4 * 4 + r;
            int gn = base + node;
            float v = fmaxf(acc2[r] + bias, 0.f);
            if (write_h && gn < N_NODES) h[(size_t)gn * HID + o] = f2bf(v);
            int gb = sbatch[node];
            if (gb != gprev) {
                if (gprev >= 0) atomicAdd(&out[gprev * 256 + out_col + o], run);
                run = 0.f;
                gprev = gb;
            }
            if (gb >= 0) run += v;
        }
    }
    if (gprev >= 0) atomicAdd(&out[gprev * 256 + out_col + o], run);
}

// ---------------------------------------------------------------------------
extern "C" void kernel_launch(void* const* d_in, const int* in_sizes, int n_in,
                              void* d_out, int out_size, void* d_ws, size_t ws_size,
                              hipStream_t stream)
{
    const int*   x        = (const int*)d_in[0];
    const int*   ei       = (const int*)d_in[1];
    const int*   ea       = (const int*)d_in[2];
    const int*   batch    = (const int*)d_in[3];
    const float* atom_emb = (const float*)d_in[4];
    const float* edge_emb = (const float*)d_in[5];
    const float* w1       = (const float*)d_in[6];
    const float* b1       = (const float*)d_in[7];
    const float* bn_g     = (const float*)d_in[8];
    const float* bn_b     = (const float*)d_in[9];
    const float* bn_m     = (const float*)d_in[10];
    const float* bn_v     = (const float*)d_in[11];
    const float* w2       = (const float*)d_in[12];
    const float* b2       = (const float*)d_in[13];
    const float* eps      = (const float*)d_in[14];

    float* out = (float*)d_out;

    // workspace layout (all chunks 16B-aligned)
    const size_t NODE_PAD = 100096;
    char* ws = (char*)d_ws;
    unsigned short* h     = (unsigned short*)ws; ws += NODE_PAD * HID * 2;            // 12.8 MB
    unsigned short* zbuf  = (unsigned short*)ws; ws += NODE_PAD * HID * 2;            // 12.8 MB
    unsigned short* comb  = (unsigned short*)ws; ws += (size_t)3 * N_COMBO * HID * 2; // 101 KB
    unsigned short* w1b   = (unsigned short*)ws; ws += (size_t)3 * MLP_HID * HID * 2;
    unsigned short* w2b   = (unsigned short*)ws; ws += (size_t)3 * HID * MLP_HID * 2;
    float* alpha          = (float*)ws;          ws += (size_t)3 * MLP_HID * 4;
    float* betab          = (float*)ws;          ws += (size_t)3 * MLP_HID * 4;
    int*   cnt            = (int*)ws;            ws += (size_t)N_NODES * 4;
    int*   off            = (int*)ws;            ws += (size_t)N_NODES * 4;
    int*   bcur           = (int*)ws;            ws += 128 * 4;
    unsigned long long* ebuf = (unsigned long long*)ws; ws += (size_t)NBUCK * BCAP * 8; // 16.1 MB
    int*   csr_e          = (int*)ws;            ws += (size_t)NBUCK * BCAP * 4;      // 8.0 MB

    const int nblk128 = (N_NODES + 127) / 128;   // 782

    zero_kernel<<<257, 256, 0, stream>>>(out, bcur);

    misc_kernel<<<NB_EMBED + NB_PREP + NB_SCAT, 256, 0, stream>>>(
        x, atom_emb, batch, h, out,
        edge_emb, w1, w2, b1, bn_g, bn_b, bn_m, bn_v,
        comb, w1b, w2b, alpha, betab,
        ei, ea, bcur, ebuf);

    csr_build_kernel<<<NBUCK, 256, 0, stream>>>(ebuf, bcur, cnt, off, csr_e);

    for (int l = 0; l < 3; ++l) {
        gather_kernel<<<N_NODES / 32, 256, 0, stream>>>(
            cnt, off, csr_e, h, comb + (size_t)l * N_COMBO * HID, eps + l, zbuf);
        mlp_kernel<<<nblk128, 256, 0, stream>>>(
            zbuf, h,
            w1b + (size_t)l * MLP_HID * HID, w2b + (size_t)l * HID * MLP_HID,
            alpha + (size_t)l * MLP_HID, betab + (size_t)l * MLP_HID,
            b2 + (size_t)l * HID, batch, out, (l + 1) * HID, (l < 2) ? 1 : 0);
    }
}